// Round 1
// baseline (2454.140 us; speedup 1.0000x reference)
//
#include <hip/hip_runtime.h>
#include <hip/hip_bf16.h>
#include <cstdint>
#include <cstddef>

static constexpr int NN = 100000;   // nodes
static constexpr int NE = 1600000;  // edges

__global__ __launch_bounds__(256) void k_deg(const int* __restrict__ row,
                                             float* __restrict__ deg, int E) {
  int i = blockIdx.x * 256 + threadIdx.x;
  if (i < E) atomicAdd(&deg[row[i]], 1.0f);
}

__global__ __launch_bounds__(256) void k_dis(float* __restrict__ deg, int N) {
  int i = blockIdx.x * 256 + threadIdx.x;
  if (i < N) deg[i] = 1.0f / sqrtf(deg[i] + 1e-12f);
}

__global__ __launch_bounds__(256) void k_norm(const int* __restrict__ row,
                                              const int* __restrict__ col,
                                              const float* __restrict__ dis,
                                              float* __restrict__ nrm, int E) {
  int e = blockIdx.x * 256 + threadIdx.x;
  if (e < E) nrm[e] = dis[row[e]] * dis[col[e]];
}

// out[r,:] = (RELU? relu(in[r,:]) : in[r,:]) @ W   ; W is KxF, staged in LDS
template <int K, int F, bool RELU>
__global__ __launch_bounds__(256) void k_gemm(const float* __restrict__ in,
                                              const float* __restrict__ W,
                                              float* __restrict__ out, int N) {
  __shared__ float Wl[K * F];
  for (int i = threadIdx.x; i < K * F; i += 256) Wl[i] = W[i];
  __syncthreads();
  int r = blockIdx.x * 256 + threadIdx.x;
  if (r >= N) return;

  float xr[K];
  const float4* xp = reinterpret_cast<const float4*>(in + (size_t)r * K);
#pragma unroll
  for (int k4 = 0; k4 < K / 4; ++k4) {
    float4 v = xp[k4];
    if (RELU) {
      v.x = fmaxf(v.x, 0.f); v.y = fmaxf(v.y, 0.f);
      v.z = fmaxf(v.z, 0.f); v.w = fmaxf(v.w, 0.f);
    }
    xr[4 * k4 + 0] = v.x; xr[4 * k4 + 1] = v.y;
    xr[4 * k4 + 2] = v.z; xr[4 * k4 + 3] = v.w;
  }

  float acc[F];
#pragma unroll
  for (int f = 0; f < F; ++f) acc[f] = 0.f;
#pragma unroll
  for (int k = 0; k < K; ++k) {
    float xk = xr[k];
#pragma unroll
    for (int f = 0; f < F; ++f) acc[f] = fmaf(xk, Wl[k * F + f], acc[f]);
  }

  float4* op = reinterpret_cast<float4*>(out + (size_t)r * F);
#pragma unroll
  for (int f4 = 0; f4 < F / 4; ++f4)
    op[f4] = make_float4(acc[4 * f4 + 0], acc[4 * f4 + 1],
                         acc[4 * f4 + 2], acc[4 * f4 + 3]);
}

// dst[row[e], :] += src[col[e], :] * nrm[e]  ; VPE float4-groups per edge (F = 4*VPE)
template <int VPE>
__global__ __launch_bounds__(256) void k_scatter(const float* __restrict__ src,
                                                 const float* __restrict__ nrm,
                                                 const int* __restrict__ row,
                                                 const int* __restrict__ col,
                                                 float* __restrict__ dst, int E) {
  int t = blockIdx.x * 256 + threadIdx.x;
  int e = t / VPE, g = t % VPE;
  if (e >= E) return;
  int c = col[e], r = row[e];
  float nv = nrm[e];
  float4 v = reinterpret_cast<const float4*>(src + (size_t)c * (VPE * 4))[g];
  float* d = dst + (size_t)r * (VPE * 4) + (size_t)g * 4;
  atomicAdd(d + 0, v.x * nv);
  atomicAdd(d + 1, v.y * nv);
  atomicAdd(d + 2, v.z * nv);
  atomicAdd(d + 3, v.w * nv);
}

extern "C" void kernel_launch(void* const* d_in, const int* in_sizes, int n_in,
                              void* d_out, int out_size, void* d_ws, size_t ws_size,
                              hipStream_t stream) {
  const float* x  = (const float*)d_in[0];
  const int*   ei = (const int*)d_in[1];
  const float* W1 = (const float*)d_in[2];
  const float* W2 = (const float*)d_in[3];
  const float* Wo = (const float*)d_in[4];
  float* out = (float*)d_out;

  const int N = NN, E = NE;
  const int* row = ei;       // edge_index[0]
  const int* col = ei + E;   // edge_index[1]

  // workspace layout (all 16B-aligned)
  float* dis  = (float*)d_ws;                       // N (deg, then deg^-1/2 in place)
  float* nrm  = dis + ((N + 63) & ~63);             // E
  float* bufA = nrm + E;                            // N*48 (xW)
  float* bufB = bufA + (size_t)N * 48;              // N*48 (accumulator)
  float* t3   = bufB + (size_t)N * 48;              // N*8

  // ---- norm ----
  hipMemsetAsync(dis, 0, sizeof(float) * (size_t)N, stream);
  k_deg<<<(E + 255) / 256, 256, 0, stream>>>(row, dis, E);
  k_dis<<<(N + 255) / 256, 256, 0, stream>>>(dis, N);
  k_norm<<<(E + 255) / 256, 256, 0, stream>>>(row, col, dis, nrm, E);

  // ---- layer 1: h1 = relu(scatter(x @ W1)) (relu folded into next gemm read) ----
  k_gemm<32, 48, false><<<(N + 255) / 256, 256, 0, stream>>>(x, W1, bufA, N);
  hipMemsetAsync(bufB, 0, sizeof(float) * (size_t)N * 48, stream);
  k_scatter<12><<<(int)(((size_t)E * 12 + 255) / 256), 256, 0, stream>>>(
      bufA, nrm, row, col, bufB, E);

  // ---- layer 2 ----
  k_gemm<48, 48, true><<<(N + 255) / 256, 256, 0, stream>>>(bufB, W2, bufA, N);
  hipMemsetAsync(bufB, 0, sizeof(float) * (size_t)N * 48, stream);
  k_scatter<12><<<(int)(((size_t)E * 12 + 255) / 256), 256, 0, stream>>>(
      bufA, nrm, row, col, bufB, E);

  // ---- output layer ----
  k_gemm<48, 8, true><<<(N + 255) / 256, 256, 0, stream>>>(bufB, Wo, t3, N);
  hipMemsetAsync(out, 0, sizeof(float) * (size_t)N * 8, stream);
  k_scatter<2><<<(int)(((size_t)E * 2 + 255) / 256), 256, 0, stream>>>(
      t3, nrm, row, col, out, E);
}

// Round 2
// 461.436 us; speedup vs baseline: 5.3185x; 5.3185x over previous
//
#include <hip/hip_runtime.h>
#include <hip/hip_bf16.h>
#include <cstdint>
#include <cstddef>

static constexpr int NN = 100000;   // nodes
static constexpr int NE = 1600000;  // edges

// ---------------- degree / norm ----------------

__global__ __launch_bounds__(256) void k_deg_int(const int* __restrict__ row,
                                                 int* __restrict__ degi, int E) {
  int i = blockIdx.x * 256 + threadIdx.x;
  if (i < E) atomicAdd(&degi[row[i]], 1);
}

__global__ __launch_bounds__(256) void k_dis(const int* __restrict__ degi,
                                             float* __restrict__ dis, int N) {
  int i = blockIdx.x * 256 + threadIdx.x;
  if (i < N) dis[i] = 1.0f / sqrtf((float)degi[i] + 1e-12f);
}

// ---------------- CSR build: two-level exclusive scan ----------------

__global__ __launch_bounds__(256) void k_bsum(const int* __restrict__ degi,
                                              int* __restrict__ bsum, int N) {
  __shared__ int s[256];
  int i = blockIdx.x * 256 + threadIdx.x;
  s[threadIdx.x] = (i < N) ? degi[i] : 0;
  __syncthreads();
  for (int off = 128; off > 0; off >>= 1) {
    if (threadIdx.x < off) s[threadIdx.x] += s[threadIdx.x + off];
    __syncthreads();
  }
  if (threadIdx.x == 0) bsum[blockIdx.x] = s[0];
}

__global__ __launch_bounds__(256) void k_scan_bsum(int* __restrict__ bsum, int nb) {
  __shared__ int s[256];
  __shared__ int carry;
  if (threadIdx.x == 0) carry = 0;
  __syncthreads();
  for (int base = 0; base < nb; base += 256) {
    int i = base + threadIdx.x;
    int v = (i < nb) ? bsum[i] : 0;
    s[threadIdx.x] = v;
    __syncthreads();
    for (int off = 1; off < 256; off <<= 1) {
      int t = (threadIdx.x >= off) ? s[threadIdx.x - off] : 0;
      __syncthreads();
      s[threadIdx.x] += t;
      __syncthreads();
    }
    int exc = carry + s[threadIdx.x] - v;
    if (i < nb) bsum[i] = exc;
    int tile_total = s[255];
    __syncthreads();
    if (threadIdx.x == 0) carry += tile_total;
    __syncthreads();
  }
}

// rowptr[i] = exclusive scan; degi becomes the fill cursor (same value).
__global__ __launch_bounds__(256) void k_scan_final(int* __restrict__ degi,
                                                    const int* __restrict__ bsum,
                                                    int* __restrict__ rowptr, int N) {
  __shared__ int s[256];
  int i = blockIdx.x * 256 + threadIdx.x;
  int v = (i < N) ? degi[i] : 0;
  s[threadIdx.x] = v;
  __syncthreads();
  for (int off = 1; off < 256; off <<= 1) {
    int t = (threadIdx.x >= off) ? s[threadIdx.x - off] : 0;
    __syncthreads();
    s[threadIdx.x] += t;
    __syncthreads();
  }
  int exc = bsum[blockIdx.x] + s[threadIdx.x] - v;
  if (i < N) {
    rowptr[i] = exc;
    degi[i] = exc;  // cursor for fill
  }
  if (i == N - 1) rowptr[N] = exc + v;
}

__global__ __launch_bounds__(256) void k_fill(const int* __restrict__ row,
                                              const int* __restrict__ col,
                                              const float* __restrict__ dis,
                                              int* __restrict__ cursor,
                                              int* __restrict__ csr_col,
                                              float* __restrict__ csr_nrm, int E) {
  int e = blockIdx.x * 256 + threadIdx.x;
  if (e >= E) return;
  int r = row[e], c = col[e];
  int pos = atomicAdd(&cursor[r], 1);
  csr_col[pos] = c;
  csr_nrm[pos] = dis[r] * dis[c];
}

// ---------------- dense GEMM: out[r,:] = (RELU? relu(in[r,:]) : in[r,:]) @ W ----------------

template <int K, int F, bool RELU>
__global__ __launch_bounds__(256) void k_gemm(const float* __restrict__ in,
                                              const float* __restrict__ W,
                                              float* __restrict__ out, int N) {
  __shared__ float Wl[K * F];
  for (int i = threadIdx.x; i < K * F; i += 256) Wl[i] = W[i];
  __syncthreads();
  int r = blockIdx.x * 256 + threadIdx.x;
  if (r >= N) return;

  float xr[K];
  const float4* xp = reinterpret_cast<const float4*>(in + (size_t)r * K);
#pragma unroll
  for (int k4 = 0; k4 < K / 4; ++k4) {
    float4 v = xp[k4];
    if (RELU) {
      v.x = fmaxf(v.x, 0.f); v.y = fmaxf(v.y, 0.f);
      v.z = fmaxf(v.z, 0.f); v.w = fmaxf(v.w, 0.f);
    }
    xr[4 * k4 + 0] = v.x; xr[4 * k4 + 1] = v.y;
    xr[4 * k4 + 2] = v.z; xr[4 * k4 + 3] = v.w;
  }

  float acc[F];
#pragma unroll
  for (int f = 0; f < F; ++f) acc[f] = 0.f;
#pragma unroll
  for (int k = 0; k < K; ++k) {
    float xk = xr[k];
#pragma unroll
    for (int f = 0; f < F; ++f) acc[f] = fmaf(xk, Wl[k * F + f], acc[f]);
  }

  float4* op = reinterpret_cast<float4*>(out + (size_t)r * F);
#pragma unroll
  for (int f4 = 0; f4 < F / 4; ++f4)
    op[f4] = make_float4(acc[4 * f4 + 0], acc[4 * f4 + 1],
                         acc[4 * f4 + 2], acc[4 * f4 + 3]);
}

// ---------------- gather conv: dst[r,:] = sum_{j in rowptr[r]..} src[csr_col[j],:]*csr_nrm[j]
// LPR lanes per row, each lane owns FQ float4s; F = LPR*FQ*4.

template <int LPR, int FQ>
__global__ __launch_bounds__(256) void k_gather(const float* __restrict__ src,
                                                const int* __restrict__ rowptr,
                                                const int* __restrict__ csr_col,
                                                const float* __restrict__ csr_nrm,
                                                float* __restrict__ dst, int N) {
  constexpr int F = LPR * FQ * 4;
  int t = blockIdx.x * 256 + threadIdx.x;
  int r = t / LPR, g = t % LPR;
  if (r >= N) return;
  int j = rowptr[r], end = rowptr[r + 1];

  float acc[FQ * 4];
#pragma unroll
  for (int q = 0; q < FQ * 4; ++q) acc[q] = 0.f;

  for (; j < end; ++j) {
    int c = csr_col[j];
    float nv = csr_nrm[j];
    const float4* sp =
        reinterpret_cast<const float4*>(src + (size_t)c * F + g * (FQ * 4));
#pragma unroll
    for (int q = 0; q < FQ; ++q) {
      float4 v = sp[q];
      acc[4 * q + 0] = fmaf(v.x, nv, acc[4 * q + 0]);
      acc[4 * q + 1] = fmaf(v.y, nv, acc[4 * q + 1]);
      acc[4 * q + 2] = fmaf(v.z, nv, acc[4 * q + 2]);
      acc[4 * q + 3] = fmaf(v.w, nv, acc[4 * q + 3]);
    }
  }

  float4* dp = reinterpret_cast<float4*>(dst + (size_t)r * F + g * (FQ * 4));
#pragma unroll
  for (int q = 0; q < FQ; ++q)
    dp[q] = make_float4(acc[4 * q + 0], acc[4 * q + 1],
                        acc[4 * q + 2], acc[4 * q + 3]);
}

// ---------------- launch ----------------

extern "C" void kernel_launch(void* const* d_in, const int* in_sizes, int n_in,
                              void* d_out, int out_size, void* d_ws, size_t ws_size,
                              hipStream_t stream) {
  const float* x  = (const float*)d_in[0];
  const int*   ei = (const int*)d_in[1];
  const float* W1 = (const float*)d_in[2];
  const float* W2 = (const float*)d_in[3];
  const float* Wo = (const float*)d_in[4];
  float* out = (float*)d_out;

  const int N = NN, E = NE;
  const int* row = ei;       // edge_index[0]
  const int* col = ei + E;   // edge_index[1]
  const int nb = (N + 255) / 256;  // 391 scan blocks

  // workspace layout (word offsets; every array 16B-aligned)
  int*   degi    = (int*)d_ws;               // N   (degree -> fill cursor)
  int*   rowptr  = degi + N;                 // N+4
  int*   bsum    = rowptr + (N + 4);         // 400
  float* dis     = (float*)(bsum + 400);     // N
  int*   csr_col = (int*)(dis + N);          // E
  float* csr_nrm = (float*)(csr_col + E);    // E
  float* bufA    = csr_nrm + E;              // N*48
  float* bufB    = bufA + (size_t)N * 48;    // N*48
  float* t3      = bufA;                     // N*8 (bufA free when used)

  // ---- degree / dis / rowptr / CSR ----
  hipMemsetAsync(degi, 0, sizeof(int) * (size_t)N, stream);
  k_deg_int<<<(E + 255) / 256, 256, 0, stream>>>(row, degi, E);
  k_dis<<<nb, 256, 0, stream>>>(degi, dis, N);
  k_bsum<<<nb, 256, 0, stream>>>(degi, bsum, N);
  k_scan_bsum<<<1, 256, 0, stream>>>(bsum, nb);
  k_scan_final<<<nb, 256, 0, stream>>>(degi, bsum, rowptr, N);
  k_fill<<<(E + 255) / 256, 256, 0, stream>>>(row, col, dis, degi, csr_col,
                                              csr_nrm, E);

  // ---- layer 1: bufB = A_norm @ (x @ W1) ----
  k_gemm<32, 48, false><<<(N + 255) / 256, 256, 0, stream>>>(x, W1, bufA, N);
  k_gather<4, 3><<<(N * 4 + 255) / 256, 256, 0, stream>>>(bufA, rowptr, csr_col,
                                                          csr_nrm, bufB, N);

  // ---- layer 2: bufB = A_norm @ (relu(bufB) @ W2) ----
  k_gemm<48, 48, true><<<(N + 255) / 256, 256, 0, stream>>>(bufB, W2, bufA, N);
  k_gather<4, 3><<<(N * 4 + 255) / 256, 256, 0, stream>>>(bufA, rowptr, csr_col,
                                                          csr_nrm, bufB, N);

  // ---- output layer: out = A_norm @ (relu(bufB) @ W_out) ----
  k_gemm<48, 8, true><<<(N + 255) / 256, 256, 0, stream>>>(bufB, Wo, t3, N);
  k_gather<2, 1><<<(N * 2 + 255) / 256, 256, 0, stream>>>(t3, rowptr, csr_col,
                                                          csr_nrm, out, N);
}

// Round 3
// 443.908 us; speedup vs baseline: 5.5285x; 1.0395x over previous
//
#include <hip/hip_runtime.h>
#include <hip/hip_bf16.h>
#include <cstdint>
#include <cstddef>

static constexpr int NN = 100000;   // nodes
static constexpr int NE = 1600000;  // edges

// ---------------- degree ----------------

__global__ __launch_bounds__(256) void k_deg_int(const int* __restrict__ row,
                                                 int* __restrict__ degi, int E) {
  int i = blockIdx.x * 256 + threadIdx.x;
  if (i < E) atomicAdd(&degi[row[i]], 1);
}

// ---------------- CSR build: two-level exclusive scan ----------------
// k_bsum also emits dis[i] = 1/sqrt(deg[i]+eps) (fused, both read degi).

__global__ __launch_bounds__(256) void k_bsum(const int* __restrict__ degi,
                                              int* __restrict__ bsum,
                                              float* __restrict__ dis, int N) {
  __shared__ int s[256];
  int i = blockIdx.x * 256 + threadIdx.x;
  int v = (i < N) ? degi[i] : 0;
  if (i < N) dis[i] = 1.0f / sqrtf((float)v + 1e-12f);
  s[threadIdx.x] = v;
  __syncthreads();
  for (int off = 128; off > 0; off >>= 1) {
    if (threadIdx.x < off) s[threadIdx.x] += s[threadIdx.x + off];
    __syncthreads();
  }
  if (threadIdx.x == 0) bsum[blockIdx.x] = s[0];
}

__global__ __launch_bounds__(256) void k_scan_bsum(int* __restrict__ bsum, int nb) {
  __shared__ int s[256];
  __shared__ int carry;
  if (threadIdx.x == 0) carry = 0;
  __syncthreads();
  for (int base = 0; base < nb; base += 256) {
    int i = base + threadIdx.x;
    int v = (i < nb) ? bsum[i] : 0;
    s[threadIdx.x] = v;
    __syncthreads();
    for (int off = 1; off < 256; off <<= 1) {
      int t = (threadIdx.x >= off) ? s[threadIdx.x - off] : 0;
      __syncthreads();
      s[threadIdx.x] += t;
      __syncthreads();
    }
    int exc = carry + s[threadIdx.x] - v;
    if (i < nb) bsum[i] = exc;
    int tile_total = s[255];
    __syncthreads();
    if (threadIdx.x == 0) carry += tile_total;
    __syncthreads();
  }
}

// rowptr[i] = exclusive scan; degi becomes the fill cursor (same value).
__global__ __launch_bounds__(256) void k_scan_final(int* __restrict__ degi,
                                                    const int* __restrict__ bsum,
                                                    int* __restrict__ rowptr, int N) {
  __shared__ int s[256];
  int i = blockIdx.x * 256 + threadIdx.x;
  int v = (i < N) ? degi[i] : 0;
  s[threadIdx.x] = v;
  __syncthreads();
  for (int off = 1; off < 256; off <<= 1) {
    int t = (threadIdx.x >= off) ? s[threadIdx.x - off] : 0;
    __syncthreads();
    s[threadIdx.x] += t;
    __syncthreads();
  }
  int exc = bsum[blockIdx.x] + s[threadIdx.x] - v;
  if (i < N) {
    rowptr[i] = exc;
    degi[i] = exc;  // cursor for fill
  }
  if (i == N - 1) rowptr[N] = exc + v;
}

// Fill only csr_col (norm factorized away: dis folded into gemm/gather epilogues).
__global__ __launch_bounds__(256) void k_fill(const int* __restrict__ row,
                                              const int* __restrict__ col,
                                              int* __restrict__ cursor,
                                              int* __restrict__ csr_col, int E) {
  int e = blockIdx.x * 256 + threadIdx.x;
  if (e >= E) return;
  int r = row[e], c = col[e];
  int pos = atomicAdd(&cursor[r], 1);
  csr_col[pos] = c;
}

// ---------------- dense GEMM with dis-scaled epilogue ----------------
// out[r,:] = dis[r] * ((RELU? relu(in[r,:]) : in[r,:]) @ W)

template <int K, int F, bool RELU>
__global__ __launch_bounds__(256) void k_gemm(const float* __restrict__ in,
                                              const float* __restrict__ W,
                                              const float* __restrict__ dis,
                                              float* __restrict__ out, int N) {
  __shared__ float Wl[K * F];
  for (int i = threadIdx.x; i < K * F; i += 256) Wl[i] = W[i];
  __syncthreads();
  int r = blockIdx.x * 256 + threadIdx.x;
  if (r >= N) return;

  float xr[K];
  const float4* xp = reinterpret_cast<const float4*>(in + (size_t)r * K);
#pragma unroll
  for (int k4 = 0; k4 < K / 4; ++k4) {
    float4 v = xp[k4];
    if (RELU) {
      v.x = fmaxf(v.x, 0.f); v.y = fmaxf(v.y, 0.f);
      v.z = fmaxf(v.z, 0.f); v.w = fmaxf(v.w, 0.f);
    }
    xr[4 * k4 + 0] = v.x; xr[4 * k4 + 1] = v.y;
    xr[4 * k4 + 2] = v.z; xr[4 * k4 + 3] = v.w;
  }

  float acc[F];
#pragma unroll
  for (int f = 0; f < F; ++f) acc[f] = 0.f;
#pragma unroll
  for (int k = 0; k < K; ++k) {
    float xk = xr[k];
#pragma unroll
    for (int f = 0; f < F; ++f) acc[f] = fmaf(xk, Wl[k * F + f], acc[f]);
  }

  float ds = dis[r];
  float4* op = reinterpret_cast<float4*>(out + (size_t)r * F);
#pragma unroll
  for (int f4 = 0; f4 < F / 4; ++f4)
    op[f4] = make_float4(ds * acc[4 * f4 + 0], ds * acc[4 * f4 + 1],
                         ds * acc[4 * f4 + 2], ds * acc[4 * f4 + 3]);
}

// ---------------- gather conv ----------------
// dst[r,:] = dis[r] * sum_{j in rowptr[r]..rowptr[r+1]} src[csr_col[j],:]
// LPR lanes per row, each lane owns FQ float4s; F = LPR*FQ*4.

template <int LPR, int FQ>
__global__ __launch_bounds__(256) void k_gather(const float* __restrict__ src,
                                                const int* __restrict__ rowptr,
                                                const int* __restrict__ csr_col,
                                                const float* __restrict__ dis,
                                                float* __restrict__ dst, int N) {
  constexpr int F = LPR * FQ * 4;
  int t = blockIdx.x * 256 + threadIdx.x;
  int r = t / LPR, g = t % LPR;
  if (r >= N) return;
  int j = rowptr[r], end = rowptr[r + 1];

  float acc[FQ * 4];
#pragma unroll
  for (int q = 0; q < FQ * 4; ++q) acc[q] = 0.f;

  for (; j < end; ++j) {
    int c = csr_col[j];
    const float4* sp =
        reinterpret_cast<const float4*>(src + (size_t)c * F + g * (FQ * 4));
#pragma unroll
    for (int q = 0; q < FQ; ++q) {
      float4 v = sp[q];
      acc[4 * q + 0] += v.x;
      acc[4 * q + 1] += v.y;
      acc[4 * q + 2] += v.z;
      acc[4 * q + 3] += v.w;
    }
  }

  float ds = dis[r];
  float4* dp = reinterpret_cast<float4*>(dst + (size_t)r * F + g * (FQ * 4));
#pragma unroll
  for (int q = 0; q < FQ; ++q)
    dp[q] = make_float4(ds * acc[4 * q + 0], ds * acc[4 * q + 1],
                        ds * acc[4 * q + 2], ds * acc[4 * q + 3]);
}

// ---------------- launch ----------------

extern "C" void kernel_launch(void* const* d_in, const int* in_sizes, int n_in,
                              void* d_out, int out_size, void* d_ws, size_t ws_size,
                              hipStream_t stream) {
  const float* x  = (const float*)d_in[0];
  const int*   ei = (const int*)d_in[1];
  const float* W1 = (const float*)d_in[2];
  const float* W2 = (const float*)d_in[3];
  const float* Wo = (const float*)d_in[4];
  float* out = (float*)d_out;

  const int N = NN, E = NE;
  const int* row = ei;       // edge_index[0]
  const int* col = ei + E;   // edge_index[1]
  const int nb = (N + 255) / 256;  // 391 scan blocks

  // workspace layout (word offsets; every array 16B-aligned)
  int*   degi    = (int*)d_ws;               // N   (degree -> fill cursor)
  int*   rowptr  = degi + N;                 // N+4
  int*   bsum    = rowptr + (N + 4);         // 400
  float* dis     = (float*)(bsum + 400);     // N
  int*   csr_col = (int*)(dis + N);          // E
  float* bufA    = (float*)(csr_col + E);    // N*48
  float* bufB    = bufA + (size_t)N * 48;    // N*48
  float* t3      = bufA;                     // N*8 (bufA free when used)

  // ---- degree / dis / rowptr / CSR ----
  hipMemsetAsync(degi, 0, sizeof(int) * (size_t)N, stream);
  k_deg_int<<<(E + 255) / 256, 256, 0, stream>>>(row, degi, E);
  k_bsum<<<nb, 256, 0, stream>>>(degi, bsum, dis, N);
  k_scan_bsum<<<1, 256, 0, stream>>>(bsum, nb);
  k_scan_final<<<nb, 256, 0, stream>>>(degi, bsum, rowptr, N);
  k_fill<<<(E + 255) / 256, 256, 0, stream>>>(row, col, degi, csr_col, E);

  // ---- layer 1: bufB = A_norm @ (x @ W1) ----
  k_gemm<32, 48, false><<<(N + 255) / 256, 256, 0, stream>>>(x, W1, dis, bufA, N);
  k_gather<4, 3><<<(N * 4 + 255) / 256, 256, 0, stream>>>(bufA, rowptr, csr_col,
                                                          dis, bufB, N);

  // ---- layer 2: bufB = A_norm @ (relu(bufB) @ W2) ----
  k_gemm<48, 48, true><<<(N + 255) / 256, 256, 0, stream>>>(bufB, W2, dis, bufA, N);
  k_gather<4, 3><<<(N * 4 + 255) / 256, 256, 0, stream>>>(bufA, rowptr, csr_col,
                                                          dis, bufB, N);

  // ---- output layer: out = A_norm @ (relu(bufB) @ W_out) ----
  k_gemm<48, 8, true><<<(N + 255) / 256, 256, 0, stream>>>(bufB, Wo, dis, t3, N);
  k_gather<2, 1><<<(N * 2 + 255) / 256, 256, 0, stream>>>(t3, rowptr, csr_col,
                                                          dis, out, N);
}

// Round 4
// 438.046 us; speedup vs baseline: 5.6025x; 1.0134x over previous
//
#include <hip/hip_runtime.h>
#include <hip/hip_bf16.h>
#include <cstdint>
#include <cstddef>

static constexpr int NN = 100000;   // nodes
static constexpr int NE = 1600000;  // edges

// ---------------- degree ----------------

__global__ __launch_bounds__(256) void k_deg_int(const int* __restrict__ row,
                                                 int* __restrict__ degi, int E) {
  int i = blockIdx.x * 256 + threadIdx.x;
  if (i < E) atomicAdd(&degi[row[i]], 1);
}

// ---------------- CSR build: two-level exclusive scan ----------------
// k_bsum also emits dis[i] = 1/sqrt(deg[i]+eps) (fused, both read degi).

__global__ __launch_bounds__(256) void k_bsum(const int* __restrict__ degi,
                                              int* __restrict__ bsum,
                                              float* __restrict__ dis, int N) {
  __shared__ int s[256];
  int i = blockIdx.x * 256 + threadIdx.x;
  int v = (i < N) ? degi[i] : 0;
  if (i < N) dis[i] = 1.0f / sqrtf((float)v + 1e-12f);
  s[threadIdx.x] = v;
  __syncthreads();
  for (int off = 128; off > 0; off >>= 1) {
    if (threadIdx.x < off) s[threadIdx.x] += s[threadIdx.x + off];
    __syncthreads();
  }
  if (threadIdx.x == 0) bsum[blockIdx.x] = s[0];
}

__global__ __launch_bounds__(256) void k_scan_bsum(int* __restrict__ bsum, int nb) {
  __shared__ int s[256];
  __shared__ int carry;
  if (threadIdx.x == 0) carry = 0;
  __syncthreads();
  for (int base = 0; base < nb; base += 256) {
    int i = base + threadIdx.x;
    int v = (i < nb) ? bsum[i] : 0;
    s[threadIdx.x] = v;
    __syncthreads();
    for (int off = 1; off < 256; off <<= 1) {
      int t = (threadIdx.x >= off) ? s[threadIdx.x - off] : 0;
      __syncthreads();
      s[threadIdx.x] += t;
      __syncthreads();
    }
    int exc = carry + s[threadIdx.x] - v;
    if (i < nb) bsum[i] = exc;
    int tile_total = s[255];
    __syncthreads();
    if (threadIdx.x == 0) carry += tile_total;
    __syncthreads();
  }
}

// rowptr[i] = exclusive scan; degi becomes the fill cursor (same value).
__global__ __launch_bounds__(256) void k_scan_final(int* __restrict__ degi,
                                                    const int* __restrict__ bsum,
                                                    int* __restrict__ rowptr, int N) {
  __shared__ int s[256];
  int i = blockIdx.x * 256 + threadIdx.x;
  int v = (i < N) ? degi[i] : 0;
  s[threadIdx.x] = v;
  __syncthreads();
  for (int off = 1; off < 256; off <<= 1) {
    int t = (threadIdx.x >= off) ? s[threadIdx.x - off] : 0;
    __syncthreads();
    s[threadIdx.x] += t;
    __syncthreads();
  }
  int exc = bsum[blockIdx.x] + s[threadIdx.x] - v;
  if (i < N) {
    rowptr[i] = exc;
    degi[i] = exc;  // cursor for fill
  }
  if (i == N - 1) rowptr[N] = exc + v;
}

// Fill csr_col. 8 edges/thread: issue 8 independent atomicAdds (512 in flight
// per wave instead of 64), THEN the 8 dependent stores — atomic-latency MLP.
__global__ __launch_bounds__(256) void k_fill(const int* __restrict__ row,
                                              const int* __restrict__ col,
                                              int* __restrict__ cursor,
                                              int* __restrict__ csr_col, int E) {
  int t = blockIdx.x * 256 + threadIdx.x;
  int base = t * 8;
  if (base + 8 <= E) {
    int4 r0 = *reinterpret_cast<const int4*>(row + base);
    int4 r1 = *reinterpret_cast<const int4*>(row + base + 4);
    int4 c0 = *reinterpret_cast<const int4*>(col + base);
    int4 c1 = *reinterpret_cast<const int4*>(col + base + 4);
    int p0 = atomicAdd(&cursor[r0.x], 1);
    int p1 = atomicAdd(&cursor[r0.y], 1);
    int p2 = atomicAdd(&cursor[r0.z], 1);
    int p3 = atomicAdd(&cursor[r0.w], 1);
    int p4 = atomicAdd(&cursor[r1.x], 1);
    int p5 = atomicAdd(&cursor[r1.y], 1);
    int p6 = atomicAdd(&cursor[r1.z], 1);
    int p7 = atomicAdd(&cursor[r1.w], 1);
    csr_col[p0] = c0.x;
    csr_col[p1] = c0.y;
    csr_col[p2] = c0.z;
    csr_col[p3] = c0.w;
    csr_col[p4] = c1.x;
    csr_col[p5] = c1.y;
    csr_col[p6] = c1.z;
    csr_col[p7] = c1.w;
  } else {
    for (int e = base; e < E; ++e) {
      int r = row[e], c = col[e];
      int pos = atomicAdd(&cursor[r], 1);
      csr_col[pos] = c;
    }
  }
}

// ---------------- dense GEMM with dis-scaled epilogue ----------------
// out[r,:] = dis[r] * ((RELU? relu(in[r,:]) : in[r,:]) @ W)

template <int K, int F, bool RELU>
__global__ __launch_bounds__(256) void k_gemm(const float* __restrict__ in,
                                              const float* __restrict__ W,
                                              const float* __restrict__ dis,
                                              float* __restrict__ out, int N) {
  __shared__ float Wl[K * F];
  for (int i = threadIdx.x; i < K * F; i += 256) Wl[i] = W[i];
  __syncthreads();
  int r = blockIdx.x * 256 + threadIdx.x;
  if (r >= N) return;

  float xr[K];
  const float4* xp = reinterpret_cast<const float4*>(in + (size_t)r * K);
#pragma unroll
  for (int k4 = 0; k4 < K / 4; ++k4) {
    float4 v = xp[k4];
    if (RELU) {
      v.x = fmaxf(v.x, 0.f); v.y = fmaxf(v.y, 0.f);
      v.z = fmaxf(v.z, 0.f); v.w = fmaxf(v.w, 0.f);
    }
    xr[4 * k4 + 0] = v.x; xr[4 * k4 + 1] = v.y;
    xr[4 * k4 + 2] = v.z; xr[4 * k4 + 3] = v.w;
  }

  float acc[F];
#pragma unroll
  for (int f = 0; f < F; ++f) acc[f] = 0.f;
#pragma unroll
  for (int k = 0; k < K; ++k) {
    float xk = xr[k];
#pragma unroll
    for (int f = 0; f < F; ++f) acc[f] = fmaf(xk, Wl[k * F + f], acc[f]);
  }

  float ds = dis[r];
  float4* op = reinterpret_cast<float4*>(out + (size_t)r * F);
#pragma unroll
  for (int f4 = 0; f4 < F / 4; ++f4)
    op[f4] = make_float4(ds * acc[4 * f4 + 0], ds * acc[4 * f4 + 1],
                         ds * acc[4 * f4 + 2], ds * acc[4 * f4 + 3]);
}

// ---------------- gather conv ----------------
// dst[r,:] = dis[r] * sum_{j in rowptr[r]..rowptr[r+1]} src[csr_col[j],:]
// LPR lanes per row, each lane owns FQ float4s; F = LPR*FQ*4.

template <int LPR, int FQ>
__global__ __launch_bounds__(256) void k_gather(const float* __restrict__ src,
                                                const int* __restrict__ rowptr,
                                                const int* __restrict__ csr_col,
                                                const float* __restrict__ dis,
                                                float* __restrict__ dst, int N) {
  constexpr int F = LPR * FQ * 4;
  int t = blockIdx.x * 256 + threadIdx.x;
  int r = t / LPR, g = t % LPR;
  if (r >= N) return;
  int j = rowptr[r], end = rowptr[r + 1];

  float acc[FQ * 4];
#pragma unroll
  for (int q = 0; q < FQ * 4; ++q) acc[q] = 0.f;

  for (; j < end; ++j) {
    int c = csr_col[j];
    const float4* sp =
        reinterpret_cast<const float4*>(src + (size_t)c * F + g * (FQ * 4));
#pragma unroll
    for (int q = 0; q < FQ; ++q) {
      float4 v = sp[q];
      acc[4 * q + 0] += v.x;
      acc[4 * q + 1] += v.y;
      acc[4 * q + 2] += v.z;
      acc[4 * q + 3] += v.w;
    }
  }

  float ds = dis[r];
  float4* dp = reinterpret_cast<float4*>(dst + (size_t)r * F + g * (FQ * 4));
#pragma unroll
  for (int q = 0; q < FQ; ++q)
    dp[q] = make_float4(ds * acc[4 * q + 0], ds * acc[4 * q + 1],
                        ds * acc[4 * q + 2], ds * acc[4 * q + 3]);
}

// ---------------- launch ----------------

extern "C" void kernel_launch(void* const* d_in, const int* in_sizes, int n_in,
                              void* d_out, int out_size, void* d_ws, size_t ws_size,
                              hipStream_t stream) {
  const float* x  = (const float*)d_in[0];
  const int*   ei = (const int*)d_in[1];
  const float* W1 = (const float*)d_in[2];
  const float* W2 = (const float*)d_in[3];
  const float* Wo = (const float*)d_in[4];
  float* out = (float*)d_out;

  const int N = NN, E = NE;
  const int* row = ei;       // edge_index[0]
  const int* col = ei + E;   // edge_index[1]
  const int nb = (N + 255) / 256;  // 391 scan blocks

  // workspace layout (word offsets; every array 16B-aligned)
  int*   degi    = (int*)d_ws;               // N   (degree -> fill cursor)
  int*   rowptr  = degi + N;                 // N+4
  int*   bsum    = rowptr + (N + 4);         // 400
  float* dis     = (float*)(bsum + 400);     // N
  int*   csr_col = (int*)(dis + N);          // E
  float* bufA    = (float*)(csr_col + E);    // N*48
  float* bufB    = bufA + (size_t)N * 48;    // N*48
  float* t3      = bufA;                     // N*8 (bufA free when used)

  // ---- degree / dis / rowptr / CSR ----
  hipMemsetAsync(degi, 0, sizeof(int) * (size_t)N, stream);
  k_deg_int<<<(E + 255) / 256, 256, 0, stream>>>(row, degi, E);
  k_bsum<<<nb, 256, 0, stream>>>(degi, bsum, dis, N);
  k_scan_bsum<<<1, 256, 0, stream>>>(bsum, nb);
  k_scan_final<<<nb, 256, 0, stream>>>(degi, bsum, rowptr, N);
  {
    int nthread = (E + 7) / 8;
    k_fill<<<(nthread + 255) / 256, 256, 0, stream>>>(row, col, degi, csr_col, E);
  }

  // ---- layer 1: bufB = A_norm @ (x @ W1) ----
  k_gemm<32, 48, false><<<(N + 255) / 256, 256, 0, stream>>>(x, W1, dis, bufA, N);
  k_gather<4, 3><<<(N * 4 + 255) / 256, 256, 0, stream>>>(bufA, rowptr, csr_col,
                                                          dis, bufB, N);

  // ---- layer 2: bufB = A_norm @ (relu(bufB) @ W2) ----
  k_gemm<48, 48, true><<<(N + 255) / 256, 256, 0, stream>>>(bufB, W2, dis, bufA, N);
  k_gather<4, 3><<<(N * 4 + 255) / 256, 256, 0, stream>>>(bufA, rowptr, csr_col,
                                                          dis, bufB, N);

  // ---- output layer: out = A_norm @ (relu(bufB) @ W_out) ----
  k_gemm<48, 8, true><<<(N + 255) / 256, 256, 0, stream>>>(bufB, Wo, dis, t3, N);
  k_gather<2, 1><<<(N * 2 + 255) / 256, 256, 0, stream>>>(t3, rowptr, csr_col,
                                                          dis, out, N);
}

// Round 5
// 287.028 us; speedup vs baseline: 8.5502x; 1.5261x over previous
//
#include <hip/hip_runtime.h>
#include <hip/hip_bf16.h>
#include <cstdint>
#include <cstddef>

static constexpr int NN = 100000;   // nodes
static constexpr int NE = 1600000;  // edges
static constexpr int NB = 391;      // buckets of 256 rows: ceil(100000/256)
static constexpr int GB = 256;      // blocks in hist/bucket passes
static constexpr int CHUNK = (NE + GB - 1) / GB;  // 6250 edges per block
static constexpr int MCNT = NB * GB;              // 100096 counts entries

// ---------------- pass A: per-(bucket,block) histogram ----------------

__global__ __launch_bounds__(256) void k_hist(const int* __restrict__ row,
                                              int* __restrict__ counts, int E) {
  __shared__ int hist[NB];
  for (int k = threadIdx.x; k < NB; k += 256) hist[k] = 0;
  __syncthreads();
  int g = blockIdx.x;
  int start = g * CHUNK, end = min(E, start + CHUNK);
  for (int i = start + threadIdx.x; i < end; i += 256)
    atomicAdd(&hist[row[i] >> 8], 1);
  __syncthreads();
  for (int k = threadIdx.x; k < NB; k += 256) counts[k * GB + g] = hist[k];
}

// ---------------- generic 2-level exclusive scan over counts ----------------

__global__ __launch_bounds__(256) void k_bsumG(const int* __restrict__ a,
                                               int* __restrict__ bsum, int M) {
  __shared__ int s[256];
  int i = blockIdx.x * 256 + threadIdx.x;
  s[threadIdx.x] = (i < M) ? a[i] : 0;
  __syncthreads();
  for (int off = 128; off > 0; off >>= 1) {
    if (threadIdx.x < off) s[threadIdx.x] += s[threadIdx.x + off];
    __syncthreads();
  }
  if (threadIdx.x == 0) bsum[blockIdx.x] = s[0];
}

__global__ __launch_bounds__(256) void k_scan_bsum(int* __restrict__ bsum, int nb) {
  __shared__ int s[256];
  __shared__ int carry;
  if (threadIdx.x == 0) carry = 0;
  __syncthreads();
  for (int base = 0; base < nb; base += 256) {
    int i = base + threadIdx.x;
    int v = (i < nb) ? bsum[i] : 0;
    s[threadIdx.x] = v;
    __syncthreads();
    for (int off = 1; off < 256; off <<= 1) {
      int t = (threadIdx.x >= off) ? s[threadIdx.x - off] : 0;
      __syncthreads();
      s[threadIdx.x] += t;
      __syncthreads();
    }
    int exc = carry + s[threadIdx.x] - v;
    if (i < nb) bsum[i] = exc;
    int tile_total = s[255];
    __syncthreads();
    if (threadIdx.x == 0) carry += tile_total;
    __syncthreads();
  }
}

__global__ __launch_bounds__(256) void k_scan_finalG(int* __restrict__ a,
                                                     const int* __restrict__ bsum,
                                                     int M) {
  __shared__ int s[256];
  int i = blockIdx.x * 256 + threadIdx.x;
  int v = (i < M) ? a[i] : 0;
  s[threadIdx.x] = v;
  __syncthreads();
  for (int off = 1; off < 256; off <<= 1) {
    int t = (threadIdx.x >= off) ? s[threadIdx.x - off] : 0;
    __syncthreads();
    s[threadIdx.x] += t;
    __syncthreads();
  }
  if (i < M) a[i] = bsum[blockIdx.x] + s[threadIdx.x] - v;
}

// ---------------- pass B: scatter edges into bucket-grouped packed array ----

__global__ __launch_bounds__(256) void k_bucket(const int* __restrict__ row,
                                                const int* __restrict__ col,
                                                const int* __restrict__ counts,
                                                unsigned int* __restrict__ packed,
                                                int E) {
  __shared__ int cur[NB];
  int g = blockIdx.x;
  for (int k = threadIdx.x; k < NB; k += 256) cur[k] = counts[k * GB + g];
  __syncthreads();
  int start = g * CHUNK, end = min(E, start + CHUNK);
  for (int i = start + threadIdx.x; i < end; i += 256) {
    int r = row[i], c = col[i];
    int b = r >> 8;
    int p = atomicAdd(&cur[b], 1);
    packed[p] = ((unsigned)(r & 255) << 17) | (unsigned)c;  // col < 2^17
  }
}

// ---------------- pass C: per-bucket CSR finalize (rowptr, dis, csr_col) ----

__global__ __launch_bounds__(256) void k_csr(const unsigned int* __restrict__ packed,
                                             const int* __restrict__ counts,
                                             int* __restrict__ rowptr,
                                             float* __restrict__ dis,
                                             int* __restrict__ csr_col,
                                             int N, int E) {
  __shared__ int rh[256];
  __shared__ int sc[256];
  __shared__ int cur[256];
  int b = blockIdx.x;
  int start = counts[b * GB];
  int end = (b + 1 < NB) ? counts[(b + 1) * GB] : E;

  rh[threadIdx.x] = 0;
  __syncthreads();
  for (int i = start + threadIdx.x; i < end; i += 256)
    atomicAdd(&rh[packed[i] >> 17], 1);
  __syncthreads();

  int v = rh[threadIdx.x];
  sc[threadIdx.x] = v;
  __syncthreads();
  for (int off = 1; off < 256; off <<= 1) {
    int t = (threadIdx.x >= off) ? sc[threadIdx.x - off] : 0;
    __syncthreads();
    sc[threadIdx.x] += t;
    __syncthreads();
  }
  int exc = sc[threadIdx.x] - v;

  int gr = (b << 8) + threadIdx.x;
  if (gr < N) {
    rowptr[gr] = start + exc;
    dis[gr] = 1.0f / sqrtf((float)v + 1e-12f);
  }
  if (b == NB - 1 && threadIdx.x == 0) rowptr[N] = E;

  cur[threadIdx.x] = exc;
  __syncthreads();
  for (int i = start + threadIdx.x; i < end; i += 256) {
    unsigned p = packed[i];
    int lr = p >> 17;
    int c = (int)(p & 0x1FFFFu);
    int pos = atomicAdd(&cur[lr], 1);
    csr_col[start + pos] = c;
  }
}

// ---------------- dense GEMM with dis-scaled epilogue ----------------
// out[r,:] = dis[r] * ((RELU? relu(in[r,:]) : in[r,:]) @ W)

template <int K, int F, bool RELU>
__global__ __launch_bounds__(256) void k_gemm(const float* __restrict__ in,
                                              const float* __restrict__ W,
                                              const float* __restrict__ dis,
                                              float* __restrict__ out, int N) {
  __shared__ float Wl[K * F];
  for (int i = threadIdx.x; i < K * F; i += 256) Wl[i] = W[i];
  __syncthreads();
  int r = blockIdx.x * 256 + threadIdx.x;
  if (r >= N) return;

  float xr[K];
  const float4* xp = reinterpret_cast<const float4*>(in + (size_t)r * K);
#pragma unroll
  for (int k4 = 0; k4 < K / 4; ++k4) {
    float4 v = xp[k4];
    if (RELU) {
      v.x = fmaxf(v.x, 0.f); v.y = fmaxf(v.y, 0.f);
      v.z = fmaxf(v.z, 0.f); v.w = fmaxf(v.w, 0.f);
    }
    xr[4 * k4 + 0] = v.x; xr[4 * k4 + 1] = v.y;
    xr[4 * k4 + 2] = v.z; xr[4 * k4 + 3] = v.w;
  }

  float acc[F];
#pragma unroll
  for (int f = 0; f < F; ++f) acc[f] = 0.f;
#pragma unroll
  for (int k = 0; k < K; ++k) {
    float xk = xr[k];
#pragma unroll
    for (int f = 0; f < F; ++f) acc[f] = fmaf(xk, Wl[k * F + f], acc[f]);
  }

  float ds = dis[r];
  float4* op = reinterpret_cast<float4*>(out + (size_t)r * F);
#pragma unroll
  for (int f4 = 0; f4 < F / 4; ++f4)
    op[f4] = make_float4(ds * acc[4 * f4 + 0], ds * acc[4 * f4 + 1],
                         ds * acc[4 * f4 + 2], ds * acc[4 * f4 + 3]);
}

// ---------------- gather conv ----------------
// dst[r,:] = dis[r] * sum_{j in rowptr[r]..rowptr[r+1]} src[csr_col[j],:]

template <int LPR, int FQ>
__global__ __launch_bounds__(256) void k_gather(const float* __restrict__ src,
                                                const int* __restrict__ rowptr,
                                                const int* __restrict__ csr_col,
                                                const float* __restrict__ dis,
                                                float* __restrict__ dst, int N) {
  constexpr int F = LPR * FQ * 4;
  int t = blockIdx.x * 256 + threadIdx.x;
  int r = t / LPR, g = t % LPR;
  if (r >= N) return;
  int j = rowptr[r], end = rowptr[r + 1];

  float acc[FQ * 4];
#pragma unroll
  for (int q = 0; q < FQ * 4; ++q) acc[q] = 0.f;

  for (; j < end; ++j) {
    int c = csr_col[j];
    const float4* sp =
        reinterpret_cast<const float4*>(src + (size_t)c * F + g * (FQ * 4));
#pragma unroll
    for (int q = 0; q < FQ; ++q) {
      float4 v = sp[q];
      acc[4 * q + 0] += v.x;
      acc[4 * q + 1] += v.y;
      acc[4 * q + 2] += v.z;
      acc[4 * q + 3] += v.w;
    }
  }

  float ds = dis[r];
  float4* dp = reinterpret_cast<float4*>(dst + (size_t)r * F + g * (FQ * 4));
#pragma unroll
  for (int q = 0; q < FQ; ++q)
    dp[q] = make_float4(ds * acc[4 * q + 0], ds * acc[4 * q + 1],
                        ds * acc[4 * q + 2], ds * acc[4 * q + 3]);
}

// ---------------- launch ----------------

extern "C" void kernel_launch(void* const* d_in, const int* in_sizes, int n_in,
                              void* d_out, int out_size, void* d_ws, size_t ws_size,
                              hipStream_t stream) {
  const float* x  = (const float*)d_in[0];
  const int*   ei = (const int*)d_in[1];
  const float* W1 = (const float*)d_in[2];
  const float* W2 = (const float*)d_in[3];
  const float* Wo = (const float*)d_in[4];
  float* out = (float*)d_out;

  const int N = NN, E = NE;
  const int* row = ei;       // edge_index[0]
  const int* col = ei + E;   // edge_index[1]

  // workspace layout (word offsets; all multiples of 4 -> 16B aligned)
  int*   counts  = (int*)d_ws;                       // MCNT = 100096
  int*   bsum    = counts + MCNT;                    // 400
  int*   rowptr  = bsum + 400;                       // 100004
  float* dis     = (float*)(rowptr + 100004);        // 100000
  int*   csr_col = (int*)(dis + 100000);             // E
  float* bufA    = (float*)(csr_col + E);            // N*48
  float* bufB    = bufA + (size_t)N * 48;            // N*48
  float* t3      = bufA;                             // N*8 (bufA free then)
  unsigned int* packed = (unsigned int*)bufA;        // E (aliases bufA, free then)

  // ---- CSR build: hist -> scan -> bucket-scatter -> per-bucket finalize ----
  k_hist<<<GB, 256, 0, stream>>>(row, counts, E);
  k_bsumG<<<MCNT / 256, 256, 0, stream>>>(counts, bsum, MCNT);
  k_scan_bsum<<<1, 256, 0, stream>>>(bsum, MCNT / 256);
  k_scan_finalG<<<MCNT / 256, 256, 0, stream>>>(counts, bsum, MCNT);
  k_bucket<<<GB, 256, 0, stream>>>(row, col, counts, packed, E);
  k_csr<<<NB, 256, 0, stream>>>(packed, counts, rowptr, dis, csr_col, N, E);

  // ---- layer 1: bufB = A_norm @ (x @ W1) ----
  k_gemm<32, 48, false><<<(N + 255) / 256, 256, 0, stream>>>(x, W1, dis, bufA, N);
  k_gather<4, 3><<<(N * 4 + 255) / 256, 256, 0, stream>>>(bufA, rowptr, csr_col,
                                                          dis, bufB, N);

  // ---- layer 2: bufB = A_norm @ (relu(bufB) @ W2) ----
  k_gemm<48, 48, true><<<(N + 255) / 256, 256, 0, stream>>>(bufB, W2, dis, bufA, N);
  k_gather<4, 3><<<(N * 4 + 255) / 256, 256, 0, stream>>>(bufA, rowptr, csr_col,
                                                          dis, bufB, N);

  // ---- output layer: out = A_norm @ (relu(bufB) @ W_out) ----
  k_gemm<48, 8, true><<<(N + 255) / 256, 256, 0, stream>>>(bufB, Wo, dis, t3, N);
  k_gather<2, 1><<<(N * 2 + 255) / 256, 256, 0, stream>>>(t3, rowptr, csr_col,
                                                          dis, out, N);
}

// Round 6
// 211.702 us; speedup vs baseline: 11.5924x; 1.3558x over previous
//
#include <hip/hip_runtime.h>
#include <hip/hip_bf16.h>
#include <cstdint>
#include <cstddef>

static constexpr int NN = 100000;   // nodes
static constexpr int NE = 1600000;  // edges
static constexpr int NB = 391;      // buckets of 256 rows
static constexpr int GB = 256;      // blocks in hist/bucket passes
static constexpr int CHUNK = (NE + GB - 1) / GB;  // 6250
static constexpr int MCNT = NB * GB;              // 100096

static __device__ __forceinline__ unsigned short f2bf(float f) {
  unsigned u = __float_as_uint(f);
  unsigned r = (u + 0x7fffu + ((u >> 16) & 1u)) >> 16;  // RNE
  return (unsigned short)r;
}

// ---------------- pass A: per-(bucket,block) histogram ----------------

__global__ __launch_bounds__(256) void k_hist(const int* __restrict__ row,
                                              int* __restrict__ counts, int E) {
  __shared__ int hist[NB];
  for (int k = threadIdx.x; k < NB; k += 256) hist[k] = 0;
  __syncthreads();
  int g = blockIdx.x;
  int start = g * CHUNK, end = min(E, start + CHUNK);
  for (int i = start + threadIdx.x; i < end; i += 256)
    atomicAdd(&hist[row[i] >> 8], 1);
  __syncthreads();
  for (int k = threadIdx.x; k < NB; k += 256) counts[k * GB + g] = hist[k];
}

// ---------------- generic 2-level exclusive scan ----------------

__global__ __launch_bounds__(256) void k_bsumG(const int* __restrict__ a,
                                               int* __restrict__ bsum, int M) {
  __shared__ int s[256];
  int i = blockIdx.x * 256 + threadIdx.x;
  s[threadIdx.x] = (i < M) ? a[i] : 0;
  __syncthreads();
  for (int off = 128; off > 0; off >>= 1) {
    if (threadIdx.x < off) s[threadIdx.x] += s[threadIdx.x + off];
    __syncthreads();
  }
  if (threadIdx.x == 0) bsum[blockIdx.x] = s[0];
}

__global__ __launch_bounds__(256) void k_scan_bsum(int* __restrict__ bsum, int nb) {
  __shared__ int s[256];
  __shared__ int carry;
  if (threadIdx.x == 0) carry = 0;
  __syncthreads();
  for (int base = 0; base < nb; base += 256) {
    int i = base + threadIdx.x;
    int v = (i < nb) ? bsum[i] : 0;
    s[threadIdx.x] = v;
    __syncthreads();
    for (int off = 1; off < 256; off <<= 1) {
      int t = (threadIdx.x >= off) ? s[threadIdx.x - off] : 0;
      __syncthreads();
      s[threadIdx.x] += t;
      __syncthreads();
    }
    int exc = carry + s[threadIdx.x] - v;
    if (i < nb) bsum[i] = exc;
    int tile_total = s[255];
    __syncthreads();
    if (threadIdx.x == 0) carry += tile_total;
    __syncthreads();
  }
}

__global__ __launch_bounds__(256) void k_scan_finalG(int* __restrict__ a,
                                                     const int* __restrict__ bsum,
                                                     int M) {
  __shared__ int s[256];
  int i = blockIdx.x * 256 + threadIdx.x;
  int v = (i < M) ? a[i] : 0;
  s[threadIdx.x] = v;
  __syncthreads();
  for (int off = 1; off < 256; off <<= 1) {
    int t = (threadIdx.x >= off) ? s[threadIdx.x - off] : 0;
    __syncthreads();
    s[threadIdx.x] += t;
    __syncthreads();
  }
  if (i < M) a[i] = bsum[blockIdx.x] + s[threadIdx.x] - v;
}

// ---------------- pass B: bucket-grouped packed edges ----------------

__global__ __launch_bounds__(256) void k_bucket(const int* __restrict__ row,
                                                const int* __restrict__ col,
                                                const int* __restrict__ counts,
                                                unsigned int* __restrict__ packed,
                                                int E) {
  __shared__ int cur[NB];
  int g = blockIdx.x;
  for (int k = threadIdx.x; k < NB; k += 256) cur[k] = counts[k * GB + g];
  __syncthreads();
  int start = g * CHUNK, end = min(E, start + CHUNK);
  for (int i = start + threadIdx.x; i < end; i += 256) {
    int r = row[i], c = col[i];
    int b = r >> 8;
    int p = atomicAdd(&cur[b], 1);
    packed[p] = ((unsigned)(r & 255) << 17) | (unsigned)c;  // col < 2^17
  }
}

// ---------------- pass C: per-bucket CSR finalize ----------------

__global__ __launch_bounds__(256) void k_csr(const unsigned int* __restrict__ packed,
                                             const int* __restrict__ counts,
                                             int* __restrict__ rowptr,
                                             float* __restrict__ dis,
                                             int* __restrict__ csr_col,
                                             int N, int E) {
  __shared__ int rh[256];
  __shared__ int sc[256];
  __shared__ int cur[256];
  int b = blockIdx.x;
  int start = counts[b * GB];
  int end = (b + 1 < NB) ? counts[(b + 1) * GB] : E;

  rh[threadIdx.x] = 0;
  __syncthreads();
  for (int i = start + threadIdx.x; i < end; i += 256)
    atomicAdd(&rh[packed[i] >> 17], 1);
  __syncthreads();

  int v = rh[threadIdx.x];
  sc[threadIdx.x] = v;
  __syncthreads();
  for (int off = 1; off < 256; off <<= 1) {
    int t = (threadIdx.x >= off) ? sc[threadIdx.x - off] : 0;
    __syncthreads();
    sc[threadIdx.x] += t;
    __syncthreads();
  }
  int exc = sc[threadIdx.x] - v;

  int gr = (b << 8) + threadIdx.x;
  if (gr < N) {
    rowptr[gr] = start + exc;
    dis[gr] = 1.0f / sqrtf((float)v + 1e-12f);
  }
  if (b == NB - 1 && threadIdx.x == 0) rowptr[N] = E;

  cur[threadIdx.x] = exc;
  __syncthreads();
  for (int i = start + threadIdx.x; i < end; i += 256) {
    unsigned p = packed[i];
    int lr = p >> 17;
    int c = (int)(p & 0x1FFFFu);
    int pos = atomicAdd(&cur[lr], 1);
    csr_col[start + pos] = c;
  }
}

// ---------------- cast+scale: xb[r,:] = bf16(dis[r] * x[r,:])  (W=32) ----------------

__global__ __launch_bounds__(256) void k_cast(const float* __restrict__ x,
                                              const float* __restrict__ dis,
                                              unsigned short* __restrict__ xb,
                                              int total /* N*32 */) {
  int i = blockIdx.x * 256 + threadIdx.x;
  int i4 = i * 4;
  if (i4 >= total) return;
  float ds = dis[i4 >> 5];
  float4 v = *reinterpret_cast<const float4*>(x + i4);
  ushort4 o;
  o.x = f2bf(v.x * ds);
  o.y = f2bf(v.y * ds);
  o.z = f2bf(v.z * ds);
  o.w = f2bf(v.w * ds);
  *reinterpret_cast<ushort4*>(xb + i4) = o;
}

// ---------------- bf16 gather: dst[r,:] = dis[r]*sum src[csr_col[j],:] ----------------
// src rows = LPR*SQ uint4 (= LPR*SQ*8 bf16); lane g owns SQ uint4s; dst f32.

template <int LPR, int SQ>
__global__ __launch_bounds__(256) void k_gather_bf(const uint4* __restrict__ src,
                                                   const int* __restrict__ rowptr,
                                                   const int* __restrict__ csr_col,
                                                   const float* __restrict__ dis,
                                                   float* __restrict__ dst, int N) {
  constexpr int RQ = LPR * SQ;   // uint4s per row
  constexpr int W = RQ * 8;      // f32 values per row
  int t = blockIdx.x * 256 + threadIdx.x;
  int r = t / LPR, g = t % LPR;
  if (r >= N) return;
  int j = rowptr[r], end = rowptr[r + 1];

  float acc[SQ * 8];
#pragma unroll
  for (int q = 0; q < SQ * 8; ++q) acc[q] = 0.f;

  for (; j < end; ++j) {
    int c = csr_col[j];
    const uint4* sp = src + (size_t)c * RQ + g * SQ;
#pragma unroll
    for (int q = 0; q < SQ; ++q) {
      uint4 u = sp[q];
      acc[8 * q + 0] += __uint_as_float(u.x << 16);
      acc[8 * q + 1] += __uint_as_float(u.x & 0xffff0000u);
      acc[8 * q + 2] += __uint_as_float(u.y << 16);
      acc[8 * q + 3] += __uint_as_float(u.y & 0xffff0000u);
      acc[8 * q + 4] += __uint_as_float(u.z << 16);
      acc[8 * q + 5] += __uint_as_float(u.z & 0xffff0000u);
      acc[8 * q + 6] += __uint_as_float(u.w << 16);
      acc[8 * q + 7] += __uint_as_float(u.w & 0xffff0000u);
    }
  }

  float ds = dis[r];
  float4* dp = reinterpret_cast<float4*>(dst + (size_t)r * W + g * (SQ * 8));
#pragma unroll
  for (int q = 0; q < SQ * 2; ++q)
    dp[q] = make_float4(ds * acc[4 * q + 0], ds * acc[4 * q + 1],
                        ds * acc[4 * q + 2], ds * acc[4 * q + 3]);
}

// ---------------- fused double GEMM: s2 = bf16(dis * (relu(g1@W1) @ W2)) ----------------

__global__ __launch_bounds__(256) void k_gemm12(const float* __restrict__ g1,
                                                const float* __restrict__ W1,
                                                const float* __restrict__ W2,
                                                const float* __restrict__ dis,
                                                unsigned short* __restrict__ s2,
                                                int N) {
  __shared__ float W1l[32 * 48];
  __shared__ float W2l[48 * 48];
  for (int i = threadIdx.x; i < 32 * 48; i += 256) W1l[i] = W1[i];
  for (int i = threadIdx.x; i < 48 * 48; i += 256) W2l[i] = W2[i];
  __syncthreads();
  int r = blockIdx.x * 256 + threadIdx.x;
  if (r >= N) return;

  float xr[32];
  const float4* xp = reinterpret_cast<const float4*>(g1 + (size_t)r * 32);
#pragma unroll
  for (int k4 = 0; k4 < 8; ++k4) {
    float4 v = xp[k4];
    xr[4 * k4 + 0] = v.x; xr[4 * k4 + 1] = v.y;
    xr[4 * k4 + 2] = v.z; xr[4 * k4 + 3] = v.w;
  }

  float h[48];
#pragma unroll
  for (int f = 0; f < 48; ++f) h[f] = 0.f;
#pragma unroll
  for (int k = 0; k < 32; ++k) {
    float xk = xr[k];
#pragma unroll
    for (int f = 0; f < 48; ++f) h[f] = fmaf(xk, W1l[k * 48 + f], h[f]);
  }
#pragma unroll
  for (int f = 0; f < 48; ++f) h[f] = fmaxf(h[f], 0.f);

  float o[48];
#pragma unroll
  for (int f = 0; f < 48; ++f) o[f] = 0.f;
#pragma unroll
  for (int k = 0; k < 48; ++k) {
    float hk = h[k];
#pragma unroll
    for (int f = 0; f < 48; ++f) o[f] = fmaf(hk, W2l[k * 48 + f], o[f]);
  }

  float ds = dis[r];
  uint4 pk[6];
  unsigned* pw = reinterpret_cast<unsigned*>(pk);
#pragma unroll
  for (int i = 0; i < 24; ++i)
    pw[i] = (unsigned)f2bf(o[2 * i] * ds) |
            ((unsigned)f2bf(o[2 * i + 1] * ds) << 16);
  uint4* op = reinterpret_cast<uint4*>(s2 + (size_t)r * 48);
#pragma unroll
  for (int q = 0; q < 6; ++q) op[q] = pk[q];
}

// ---------------- f32 GEMM with relu-in + dis epilogue (layer 3) ----------------

template <int K, int F, bool RELU>
__global__ __launch_bounds__(256) void k_gemm(const float* __restrict__ in,
                                              const float* __restrict__ W,
                                              const float* __restrict__ dis,
                                              float* __restrict__ out, int N) {
  __shared__ float Wl[K * F];
  for (int i = threadIdx.x; i < K * F; i += 256) Wl[i] = W[i];
  __syncthreads();
  int r = blockIdx.x * 256 + threadIdx.x;
  if (r >= N) return;

  float xr[K];
  const float4* xp = reinterpret_cast<const float4*>(in + (size_t)r * K);
#pragma unroll
  for (int k4 = 0; k4 < K / 4; ++k4) {
    float4 v = xp[k4];
    if (RELU) {
      v.x = fmaxf(v.x, 0.f); v.y = fmaxf(v.y, 0.f);
      v.z = fmaxf(v.z, 0.f); v.w = fmaxf(v.w, 0.f);
    }
    xr[4 * k4 + 0] = v.x; xr[4 * k4 + 1] = v.y;
    xr[4 * k4 + 2] = v.z; xr[4 * k4 + 3] = v.w;
  }

  float acc[F];
#pragma unroll
  for (int f = 0; f < F; ++f) acc[f] = 0.f;
#pragma unroll
  for (int k = 0; k < K; ++k) {
    float xk = xr[k];
#pragma unroll
    for (int f = 0; f < F; ++f) acc[f] = fmaf(xk, Wl[k * F + f], acc[f]);
  }

  float ds = dis[r];
  float4* op = reinterpret_cast<float4*>(out + (size_t)r * F);
#pragma unroll
  for (int f4 = 0; f4 < F / 4; ++f4)
    op[f4] = make_float4(ds * acc[4 * f4 + 0], ds * acc[4 * f4 + 1],
                         ds * acc[4 * f4 + 2], ds * acc[4 * f4 + 3]);
}

// ---------------- f32 gather (final 8-wide layer) ----------------

template <int LPR, int FQ>
__global__ __launch_bounds__(256) void k_gather(const float* __restrict__ src,
                                                const int* __restrict__ rowptr,
                                                const int* __restrict__ csr_col,
                                                const float* __restrict__ dis,
                                                float* __restrict__ dst, int N) {
  constexpr int F = LPR * FQ * 4;
  int t = blockIdx.x * 256 + threadIdx.x;
  int r = t / LPR, g = t % LPR;
  if (r >= N) return;
  int j = rowptr[r], end = rowptr[r + 1];

  float acc[FQ * 4];
#pragma unroll
  for (int q = 0; q < FQ * 4; ++q) acc[q] = 0.f;

  for (; j < end; ++j) {
    int c = csr_col[j];
    const float4* sp =
        reinterpret_cast<const float4*>(src + (size_t)c * F + g * (FQ * 4));
#pragma unroll
    for (int q = 0; q < FQ; ++q) {
      float4 v = sp[q];
      acc[4 * q + 0] += v.x;
      acc[4 * q + 1] += v.y;
      acc[4 * q + 2] += v.z;
      acc[4 * q + 3] += v.w;
    }
  }

  float ds = dis[r];
  float4* dp = reinterpret_cast<float4*>(dst + (size_t)r * F + g * (FQ * 4));
#pragma unroll
  for (int q = 0; q < FQ; ++q)
    dp[q] = make_float4(ds * acc[4 * q + 0], ds * acc[4 * q + 1],
                        ds * acc[4 * q + 2], ds * acc[4 * q + 3]);
}

// ---------------- launch ----------------

extern "C" void kernel_launch(void* const* d_in, const int* in_sizes, int n_in,
                              void* d_out, int out_size, void* d_ws, size_t ws_size,
                              hipStream_t stream) {
  const float* x  = (const float*)d_in[0];
  const int*   ei = (const int*)d_in[1];
  const float* W1 = (const float*)d_in[2];
  const float* W2 = (const float*)d_in[3];
  const float* Wo = (const float*)d_in[4];
  float* out = (float*)d_out;

  const int N = NN, E = NE;
  const int* row = ei;
  const int* col = ei + E;

  // workspace (floats/words)
  int*   counts  = (int*)d_ws;                   // 100096
  int*   bsum    = counts + MCNT;                // 400
  int*   rowptr  = bsum + 400;                   // 100004
  float* dis     = (float*)(rowptr + 100004);    // 100000
  int*   csr_col = (int*)(dis + 100000);         // 1.6M
  float* A1      = (float*)(csr_col + NE);       // 4.8M floats
  float* A2      = A1 + 4800000;                 // 4.8M floats
  // aliases (lifetimes disjoint):
  unsigned int*  packed = (unsigned int*)A1;             // CSR build only
  unsigned short* s2    = (unsigned short*)A1;           // N*48 bf16
  float*          s3    = A1;                            // N*8 f32
  float*          g1    = A2;                            // N*32 f32
  unsigned short* xb    = (unsigned short*)(A2 + 3200000); // N*32 bf16
  float*          g2    = A2;                            // N*48 f32

  // ---- CSR build ----
  k_hist<<<GB, 256, 0, stream>>>(row, counts, E);
  k_bsumG<<<MCNT / 256, 256, 0, stream>>>(counts, bsum, MCNT);
  k_scan_bsum<<<1, 256, 0, stream>>>(bsum, MCNT / 256);
  k_scan_finalG<<<MCNT / 256, 256, 0, stream>>>(counts, bsum, MCNT);
  k_bucket<<<GB, 256, 0, stream>>>(row, col, counts, packed, E);
  k_csr<<<NB, 256, 0, stream>>>(packed, counts, rowptr, dis, csr_col, N, E);

  // ---- layer 1 (reassociated): g1 = dis⊙(Ā@(dis⊙x)) ----
  k_cast<<<(N * 32 / 4 + 255) / 256, 256, 0, stream>>>(x, dis, xb, N * 32);
  k_gather_bf<2, 2><<<(N * 2 + 255) / 256, 256, 0, stream>>>(
      (const uint4*)xb, rowptr, csr_col, dis, g1, N);

  // ---- fused GEMM1+GEMM2: s2 = bf16(dis * (relu(g1@W1)@W2)) ----
  k_gemm12<<<(N + 255) / 256, 256, 0, stream>>>(g1, W1, W2, dis, s2, N);

  // ---- layer 2 gather: g2 = dis⊙(Ā@s2)  (h2 = relu(g2) deferred to gemm3) ----
  k_gather_bf<2, 3><<<(N * 2 + 255) / 256, 256, 0, stream>>>(
      (const uint4*)s2, rowptr, csr_col, dis, g2, N);

  // ---- layer 3: s3 = dis*(relu(g2)@Wo); out = dis⊙(Ā@s3) ----
  k_gemm<48, 8, true><<<(N + 255) / 256, 256, 0, stream>>>(g2, Wo, dis, s3, N);
  k_gather<2, 1><<<(N * 2 + 255) / 256, 256, 0, stream>>>(s3, rowptr, csr_col,
                                                          dis, out, N);
}

// Round 7
// 184.574 us; speedup vs baseline: 13.2962x; 1.1470x over previous
//
#include <hip/hip_runtime.h>
#include <hip/hip_bf16.h>
#include <cstdint>
#include <cstddef>

static constexpr int NN = 100000;   // nodes
static constexpr int NE = 1600000;  // edges
static constexpr int NB = 391;      // buckets of 256 rows
static constexpr int GB = 250;      // blocks in hist/bucket passes (250*6400 == NE)
static constexpr int CHUNK = NE / GB;             // 6400 (int4-aligned chunks)
static constexpr int MCNT = NB * GB;              // 97750

static __device__ __forceinline__ unsigned short f2bf(float f) {
  unsigned u = __float_as_uint(f);
  unsigned r = (u + 0x7fffu + ((u >> 16) & 1u)) >> 16;  // RNE
  return (unsigned short)r;
}

// ---------------- pass A: per-(bucket,block) histogram (int4 reads) ----------------

__global__ __launch_bounds__(256) void k_hist(const int* __restrict__ row,
                                              int* __restrict__ counts) {
  __shared__ int hist[NB];
  for (int k = threadIdx.x; k < NB; k += 256) hist[k] = 0;
  __syncthreads();
  int g = blockIdx.x;
  int start = g * CHUNK;
  for (int gi = threadIdx.x; gi < CHUNK / 4; gi += 256) {
    int4 r4 = *reinterpret_cast<const int4*>(row + start + gi * 4);
    atomicAdd(&hist[r4.x >> 8], 1);
    atomicAdd(&hist[r4.y >> 8], 1);
    atomicAdd(&hist[r4.z >> 8], 1);
    atomicAdd(&hist[r4.w >> 8], 1);
  }
  __syncthreads();
  for (int k = threadIdx.x; k < NB; k += 256) counts[k * GB + g] = hist[k];
}

// ---------------- generic 2-level exclusive scan ----------------

__global__ __launch_bounds__(256) void k_bsumG(const int* __restrict__ a,
                                               int* __restrict__ bsum, int M) {
  __shared__ int s[256];
  int i = blockIdx.x * 256 + threadIdx.x;
  s[threadIdx.x] = (i < M) ? a[i] : 0;
  __syncthreads();
  for (int off = 128; off > 0; off >>= 1) {
    if (threadIdx.x < off) s[threadIdx.x] += s[threadIdx.x + off];
    __syncthreads();
  }
  if (threadIdx.x == 0) bsum[blockIdx.x] = s[0];
}

__global__ __launch_bounds__(256) void k_scan_bsum(int* __restrict__ bsum, int nb) {
  __shared__ int s[256];
  __shared__ int carry;
  if (threadIdx.x == 0) carry = 0;
  __syncthreads();
  for (int base = 0; base < nb; base += 256) {
    int i = base + threadIdx.x;
    int v = (i < nb) ? bsum[i] : 0;
    s[threadIdx.x] = v;
    __syncthreads();
    for (int off = 1; off < 256; off <<= 1) {
      int t = (threadIdx.x >= off) ? s[threadIdx.x - off] : 0;
      __syncthreads();
      s[threadIdx.x] += t;
      __syncthreads();
    }
    int exc = carry + s[threadIdx.x] - v;
    if (i < nb) bsum[i] = exc;
    int tile_total = s[255];
    __syncthreads();
    if (threadIdx.x == 0) carry += tile_total;
    __syncthreads();
  }
}

__global__ __launch_bounds__(256) void k_scan_finalG(int* __restrict__ a,
                                                     const int* __restrict__ bsum,
                                                     int M) {
  __shared__ int s[256];
  int i = blockIdx.x * 256 + threadIdx.x;
  int v = (i < M) ? a[i] : 0;
  s[threadIdx.x] = v;
  __syncthreads();
  for (int off = 1; off < 256; off <<= 1) {
    int t = (threadIdx.x >= off) ? s[threadIdx.x - off] : 0;
    __syncthreads();
    s[threadIdx.x] += t;
    __syncthreads();
  }
  if (i < M) a[i] = bsum[blockIdx.x] + s[threadIdx.x] - v;
}

// ---------------- pass B: bucket-grouped packed edges (int4 reads) ----------------

__global__ __launch_bounds__(256) void k_bucket(const int* __restrict__ row,
                                                const int* __restrict__ col,
                                                const int* __restrict__ counts,
                                                unsigned int* __restrict__ packed) {
  __shared__ int cur[NB];
  int g = blockIdx.x;
  for (int k = threadIdx.x; k < NB; k += 256) cur[k] = counts[k * GB + g];
  __syncthreads();
  int start = g * CHUNK;
  for (int gi = threadIdx.x; gi < CHUNK / 4; gi += 256) {
    int4 r4 = *reinterpret_cast<const int4*>(row + start + gi * 4);
    int4 c4 = *reinterpret_cast<const int4*>(col + start + gi * 4);
    int p0 = atomicAdd(&cur[r4.x >> 8], 1);
    int p1 = atomicAdd(&cur[r4.y >> 8], 1);
    int p2 = atomicAdd(&cur[r4.z >> 8], 1);
    int p3 = atomicAdd(&cur[r4.w >> 8], 1);
    packed[p0] = ((unsigned)(r4.x & 255) << 17) | (unsigned)c4.x;
    packed[p1] = ((unsigned)(r4.y & 255) << 17) | (unsigned)c4.y;
    packed[p2] = ((unsigned)(r4.z & 255) << 17) | (unsigned)c4.z;
    packed[p3] = ((unsigned)(r4.w & 255) << 17) | (unsigned)c4.w;
  }
}

// ---------------- pass C: per-bucket CSR finalize + fused x-cast ----------------
// Also emits xb[r,:] = bf16(dis[r] * x[r,:]) for this bucket's 256 rows.

__global__ __launch_bounds__(256) void k_csr(const unsigned int* __restrict__ packed,
                                             const int* __restrict__ counts,
                                             int* __restrict__ rowptr,
                                             float* __restrict__ dis,
                                             int* __restrict__ csr_col,
                                             const float* __restrict__ x,
                                             unsigned short* __restrict__ xb,
                                             int N, int E) {
  __shared__ int rh[256];
  __shared__ int sc[256];
  __shared__ int cur[256];
  __shared__ float ldis[256];
  int b = blockIdx.x;
  int start = counts[b * GB];
  int end = (b + 1 < NB) ? counts[(b + 1) * GB] : E;

  rh[threadIdx.x] = 0;
  __syncthreads();
  for (int i = start + threadIdx.x; i < end; i += 256)
    atomicAdd(&rh[packed[i] >> 17], 1);
  __syncthreads();

  int v = rh[threadIdx.x];
  sc[threadIdx.x] = v;
  __syncthreads();
  for (int off = 1; off < 256; off <<= 1) {
    int t = (threadIdx.x >= off) ? sc[threadIdx.x - off] : 0;
    __syncthreads();
    sc[threadIdx.x] += t;
    __syncthreads();
  }
  int exc = sc[threadIdx.x] - v;

  float dv = 1.0f / sqrtf((float)v + 1e-12f);
  ldis[threadIdx.x] = dv;
  int gr = (b << 8) + threadIdx.x;
  if (gr < N) {
    rowptr[gr] = start + exc;
    dis[gr] = dv;
  }
  if (b == NB - 1 && threadIdx.x == 0) rowptr[N] = E;

  cur[threadIdx.x] = exc;
  __syncthreads();
  for (int i = start + threadIdx.x; i < end; i += 256) {
    unsigned p = packed[i];
    int lr = p >> 17;
    int c = (int)(p & 0x1FFFFu);
    int pos = atomicAdd(&cur[lr], 1);
    csr_col[start + pos] = c;
  }

  // fused cast: this bucket's rows of x -> bf16 * dis  (coalesced float4 loop)
  int rows = min(256, N - (b << 8));
  if (rows > 0) {
    const float4* xs = reinterpret_cast<const float4*>(x + ((size_t)b << 8) * 32);
    ushort4* xd = reinterpret_cast<ushort4*>(xb + ((size_t)b << 8) * 32);
    for (int i = threadIdx.x; i < rows * 8; i += 256) {
      float ds = ldis[i >> 3];
      float4 vv = xs[i];
      xd[i] = make_ushort4(f2bf(vv.x * ds), f2bf(vv.y * ds),
                           f2bf(vv.z * ds), f2bf(vv.w * ds));
    }
  }
}

// ---------------- bf16 gather: dst[r,:] = dis[r]*sum src[csr_col[j],:] ----------------
// src rows = LPR*SQ uint4; lane g owns SQ uint4s; dst f32.

template <int LPR, int SQ>
__global__ __launch_bounds__(256) void k_gather_bf(const uint4* __restrict__ src,
                                                   const int* __restrict__ rowptr,
                                                   const int* __restrict__ csr_col,
                                                   const float* __restrict__ dis,
                                                   float* __restrict__ dst, int N) {
  constexpr int RQ = LPR * SQ;   // uint4s per row
  constexpr int W = RQ * 8;      // f32 values per row
  int t = blockIdx.x * 256 + threadIdx.x;
  int r = t / LPR, g = t % LPR;
  if (r >= N) return;
  int j = rowptr[r], end = rowptr[r + 1];

  float acc[SQ * 8];
#pragma unroll
  for (int q = 0; q < SQ * 8; ++q) acc[q] = 0.f;

  for (; j < end; ++j) {
    int c = csr_col[j];
    const uint4* sp = src + (size_t)c * RQ + g * SQ;
#pragma unroll
    for (int q = 0; q < SQ; ++q) {
      uint4 u = sp[q];
      acc[8 * q + 0] += __uint_as_float(u.x << 16);
      acc[8 * q + 1] += __uint_as_float(u.x & 0xffff0000u);
      acc[8 * q + 2] += __uint_as_float(u.y << 16);
      acc[8 * q + 3] += __uint_as_float(u.y & 0xffff0000u);
      acc[8 * q + 4] += __uint_as_float(u.z << 16);
      acc[8 * q + 5] += __uint_as_float(u.z & 0xffff0000u);
      acc[8 * q + 6] += __uint_as_float(u.w << 16);
      acc[8 * q + 7] += __uint_as_float(u.w & 0xffff0000u);
    }
  }

  float ds = dis[r];
  float4* dp = reinterpret_cast<float4*>(dst + (size_t)r * W + g * (SQ * 8));
#pragma unroll
  for (int q = 0; q < SQ * 2; ++q)
    dp[q] = make_float4(ds * acc[4 * q + 0], ds * acc[4 * q + 1],
                        ds * acc[4 * q + 2], ds * acc[4 * q + 3]);
}

// ---------------- fused double GEMM: s2 = bf16(dis * (relu(g1@W1) @ W2)) ----------------

__global__ __launch_bounds__(256) void k_gemm12(const float* __restrict__ g1,
                                                const float* __restrict__ W1,
                                                const float* __restrict__ W2,
                                                const float* __restrict__ dis,
                                                unsigned short* __restrict__ s2,
                                                int N) {
  __shared__ float W1l[32 * 48];
  __shared__ float W2l[48 * 48];
  for (int i = threadIdx.x; i < 32 * 48; i += 256) W1l[i] = W1[i];
  for (int i = threadIdx.x; i < 48 * 48; i += 256) W2l[i] = W2[i];
  __syncthreads();
  int r = blockIdx.x * 256 + threadIdx.x;
  if (r >= N) return;

  float xr[32];
  const float4* xp = reinterpret_cast<const float4*>(g1 + (size_t)r * 32);
#pragma unroll
  for (int k4 = 0; k4 < 8; ++k4) {
    float4 v = xp[k4];
    xr[4 * k4 + 0] = v.x; xr[4 * k4 + 1] = v.y;
    xr[4 * k4 + 2] = v.z; xr[4 * k4 + 3] = v.w;
  }

  float h[48];
#pragma unroll
  for (int f = 0; f < 48; ++f) h[f] = 0.f;
#pragma unroll
  for (int k = 0; k < 32; ++k) {
    float xk = xr[k];
#pragma unroll
    for (int f = 0; f < 48; ++f) h[f] = fmaf(xk, W1l[k * 48 + f], h[f]);
  }
#pragma unroll
  for (int f = 0; f < 48; ++f) h[f] = fmaxf(h[f], 0.f);

  float o[48];
#pragma unroll
  for (int f = 0; f < 48; ++f) o[f] = 0.f;
#pragma unroll
  for (int k = 0; k < 48; ++k) {
    float hk = h[k];
#pragma unroll
    for (int f = 0; f < 48; ++f) o[f] = fmaf(hk, W2l[k * 48 + f], o[f]);
  }

  float ds = dis[r];
  uint4 pk[6];
  unsigned* pw = reinterpret_cast<unsigned*>(pk);
#pragma unroll
  for (int i = 0; i < 24; ++i)
    pw[i] = (unsigned)f2bf(o[2 * i] * ds) |
            ((unsigned)f2bf(o[2 * i + 1] * ds) << 16);
  uint4* op = reinterpret_cast<uint4*>(s2 + (size_t)r * 48);
#pragma unroll
  for (int q = 0; q < 6; ++q) op[q] = pk[q];
}

// ---------------- f32 GEMM with relu-in + dis epilogue (layer 3) ----------------

template <int K, int F, bool RELU>
__global__ __launch_bounds__(256) void k_gemm(const float* __restrict__ in,
                                              const float* __restrict__ W,
                                              const float* __restrict__ dis,
                                              float* __restrict__ out, int N) {
  __shared__ float Wl[K * F];
  for (int i = threadIdx.x; i < K * F; i += 256) Wl[i] = W[i];
  __syncthreads();
  int r = blockIdx.x * 256 + threadIdx.x;
  if (r >= N) return;

  float xr[K];
  const float4* xp = reinterpret_cast<const float4*>(in + (size_t)r * K);
#pragma unroll
  for (int k4 = 0; k4 < K / 4; ++k4) {
    float4 v = xp[k4];
    if (RELU) {
      v.x = fmaxf(v.x, 0.f); v.y = fmaxf(v.y, 0.f);
      v.z = fmaxf(v.z, 0.f); v.w = fmaxf(v.w, 0.f);
    }
    xr[4 * k4 + 0] = v.x; xr[4 * k4 + 1] = v.y;
    xr[4 * k4 + 2] = v.z; xr[4 * k4 + 3] = v.w;
  }

  float acc[F];
#pragma unroll
  for (int f = 0; f < F; ++f) acc[f] = 0.f;
#pragma unroll
  for (int k = 0; k < K; ++k) {
    float xk = xr[k];
#pragma unroll
    for (int f = 0; f < F; ++f) acc[f] = fmaf(xk, Wl[k * F + f], acc[f]);
  }

  float ds = dis[r];
  float4* op = reinterpret_cast<float4*>(out + (size_t)r * F);
#pragma unroll
  for (int f4 = 0; f4 < F / 4; ++f4)
    op[f4] = make_float4(ds * acc[4 * f4 + 0], ds * acc[4 * f4 + 1],
                         ds * acc[4 * f4 + 2], ds * acc[4 * f4 + 3]);
}

// ---------------- f32 gather (final 8-wide layer) ----------------

template <int LPR, int FQ>
__global__ __launch_bounds__(256) void k_gather(const float* __restrict__ src,
                                                const int* __restrict__ rowptr,
                                                const int* __restrict__ csr_col,
                                                const float* __restrict__ dis,
                                                float* __restrict__ dst, int N) {
  constexpr int F = LPR * FQ * 4;
  int t = blockIdx.x * 256 + threadIdx.x;
  int r = t / LPR, g = t % LPR;
  if (r >= N) return;
  int j = rowptr[r], end = rowptr[r + 1];

  float acc[FQ * 4];
#pragma unroll
  for (int q = 0; q < FQ * 4; ++q) acc[q] = 0.f;

  for (; j < end; ++j) {
    int c = csr_col[j];
    const float4* sp =
        reinterpret_cast<const float4*>(src + (size_t)c * F + g * (FQ * 4));
#pragma unroll
    for (int q = 0; q < FQ; ++q) {
      float4 v = sp[q];
      acc[4 * q + 0] += v.x;
      acc[4 * q + 1] += v.y;
      acc[4 * q + 2] += v.z;
      acc[4 * q + 3] += v.w;
    }
  }

  float ds = dis[r];
  float4* dp = reinterpret_cast<float4*>(dst + (size_t)r * F + g * (FQ * 4));
#pragma unroll
  for (int q = 0; q < FQ; ++q)
    dp[q] = make_float4(ds * acc[4 * q + 0], ds * acc[4 * q + 1],
                        ds * acc[4 * q + 2], ds * acc[4 * q + 3]);
}

// ---------------- launch ----------------

extern "C" void kernel_launch(void* const* d_in, const int* in_sizes, int n_in,
                              void* d_out, int out_size, void* d_ws, size_t ws_size,
                              hipStream_t stream) {
  const float* x  = (const float*)d_in[0];
  const int*   ei = (const int*)d_in[1];
  const float* W1 = (const float*)d_in[2];
  const float* W2 = (const float*)d_in[3];
  const float* Wo = (const float*)d_in[4];
  float* out = (float*)d_out;

  const int N = NN, E = NE;
  const int* row = ei;
  const int* col = ei + E;
  const int scanG = (MCNT + 255) / 256;  // 382

  // workspace (words; every array 16B-aligned)
  int*   counts  = (int*)d_ws;                   // 97750 (pad 97752)
  int*   bsum    = counts + 97752;               // 382 (pad 384)
  int*   rowptr  = bsum + 384;                   // 100001 (pad 100008)
  float* dis     = (float*)(rowptr + 100008);    // 100000
  int*   csr_col = (int*)(dis + 100000);         // 1.6M
  float* A1      = (float*)(csr_col + NE);       // 4.8M floats
  float* A2      = A1 + 4800000;                 // 4.8M floats
  // aliases (lifetimes disjoint):
  unsigned int*   packed = (unsigned int*)A1;              // CSR build only
  unsigned short* s2     = (unsigned short*)A1;            // N*48 bf16
  float*          s3     = A1;                             // N*8 f32
  float*          g1     = A2;                             // N*32 f32
  unsigned short* xb     = (unsigned short*)(A2 + 3200000);// N*32 bf16
  float*          g2     = A2;                             // N*48 f32

  // ---- CSR build (+fused cast) ----
  k_hist<<<GB, 256, 0, stream>>>(row, counts);
  k_bsumG<<<scanG, 256, 0, stream>>>(counts, bsum, MCNT);
  k_scan_bsum<<<1, 256, 0, stream>>>(bsum, scanG);
  k_scan_finalG<<<scanG, 256, 0, stream>>>(counts, bsum, MCNT);
  k_bucket<<<GB, 256, 0, stream>>>(row, col, counts, packed);
  k_csr<<<NB, 256, 0, stream>>>(packed, counts, rowptr, dis, csr_col, x, xb, N, E);

  // ---- layer 1 (reassociated): g1 = dis⊙(Ā@(dis⊙x)) ----
  k_gather_bf<4, 1><<<(N * 4 + 255) / 256, 256, 0, stream>>>(
      (const uint4*)xb, rowptr, csr_col, dis, g1, N);

  // ---- fused GEMM1+GEMM2: s2 = bf16(dis * (relu(g1@W1)@W2)) ----
  k_gemm12<<<(N + 255) / 256, 256, 0, stream>>>(g1, W1, W2, dis, s2, N);

  // ---- layer 2 gather: g2 = dis⊙(Ā@s2) ----
  k_gather_bf<3, 2><<<(N * 3 + 255) / 256, 256, 0, stream>>>(
      (const uint4*)s2, rowptr, csr_col, dis, g2, N);

  // ---- layer 3: s3 = dis*(relu(g2)@Wo); out = dis⊙(Ā@s3) ----
  k_gemm<48, 8, true><<<(N + 255) / 256, 256, 0, stream>>>(g2, Wo, dis, s3, N);
  k_gather<2, 1><<<(N * 2 + 255) / 256, 256, 0, stream>>>(s3, rowptr, csr_col,
                                                          dis, out, N);
}

// Round 8
// 174.814 us; speedup vs baseline: 14.0386x; 1.0558x over previous
//
#include <hip/hip_runtime.h>
#include <hip/hip_bf16.h>
#include <cstdint>
#include <cstddef>

static constexpr int NN = 100000;   // nodes
static constexpr int NE = 1600000;  // edges
static constexpr int NB = 391;      // buckets of 256 rows
static constexpr int GB = 250;      // blocks in hist/bucket passes (250*6400 == NE)
static constexpr int CHUNK = NE / GB;             // 6400 (int4-aligned chunks)
static constexpr int MCNT = NB * GB;              // 97750

static __device__ __forceinline__ unsigned short f2bf(float f) {
  unsigned u = __float_as_uint(f);
  unsigned r = (u + 0x7fffu + ((u >> 16) & 1u)) >> 16;  // RNE
  return (unsigned short)r;
}

// ---------------- pass A: per-(bucket,block) histogram (int4 reads) ----------------

__global__ __launch_bounds__(256) void k_hist(const int* __restrict__ row,
                                              int* __restrict__ counts) {
  __shared__ int hist[NB];
  for (int k = threadIdx.x; k < NB; k += 256) hist[k] = 0;
  __syncthreads();
  int g = blockIdx.x;
  int start = g * CHUNK;
  for (int gi = threadIdx.x; gi < CHUNK / 4; gi += 256) {
    int4 r4 = *reinterpret_cast<const int4*>(row + start + gi * 4);
    atomicAdd(&hist[r4.x >> 8], 1);
    atomicAdd(&hist[r4.y >> 8], 1);
    atomicAdd(&hist[r4.z >> 8], 1);
    atomicAdd(&hist[r4.w >> 8], 1);
  }
  __syncthreads();
  for (int k = threadIdx.x; k < NB; k += 256) counts[k * GB + g] = hist[k];
}

// ---------------- generic 2-level exclusive scan ----------------

__global__ __launch_bounds__(256) void k_bsumG(const int* __restrict__ a,
                                               int* __restrict__ bsum, int M) {
  __shared__ int s[256];
  int i = blockIdx.x * 256 + threadIdx.x;
  s[threadIdx.x] = (i < M) ? a[i] : 0;
  __syncthreads();
  for (int off = 128; off > 0; off >>= 1) {
    if (threadIdx.x < off) s[threadIdx.x] += s[threadIdx.x + off];
    __syncthreads();
  }
  if (threadIdx.x == 0) bsum[blockIdx.x] = s[0];
}

__global__ __launch_bounds__(256) void k_scan_bsum(int* __restrict__ bsum, int nb) {
  __shared__ int s[256];
  __shared__ int carry;
  if (threadIdx.x == 0) carry = 0;
  __syncthreads();
  for (int base = 0; base < nb; base += 256) {
    int i = base + threadIdx.x;
    int v = (i < nb) ? bsum[i] : 0;
    s[threadIdx.x] = v;
    __syncthreads();
    for (int off = 1; off < 256; off <<= 1) {
      int t = (threadIdx.x >= off) ? s[threadIdx.x - off] : 0;
      __syncthreads();
      s[threadIdx.x] += t;
      __syncthreads();
    }
    int exc = carry + s[threadIdx.x] - v;
    if (i < nb) bsum[i] = exc;
    int tile_total = s[255];
    __syncthreads();
    if (threadIdx.x == 0) carry += tile_total;
    __syncthreads();
  }
}

__global__ __launch_bounds__(256) void k_scan_finalG(int* __restrict__ a,
                                                     const int* __restrict__ bsum,
                                                     int M) {
  __shared__ int s[256];
  int i = blockIdx.x * 256 + threadIdx.x;
  int v = (i < M) ? a[i] : 0;
  s[threadIdx.x] = v;
  __syncthreads();
  for (int off = 1; off < 256; off <<= 1) {
    int t = (threadIdx.x >= off) ? s[threadIdx.x - off] : 0;
    __syncthreads();
    s[threadIdx.x] += t;
    __syncthreads();
  }
  if (i < M) a[i] = bsum[blockIdx.x] + s[threadIdx.x] - v;
}

// ---------------- pass B: bucket-grouped packed edges (int4 reads) ----------------

__global__ __launch_bounds__(256) void k_bucket(const int* __restrict__ row,
                                                const int* __restrict__ col,
                                                const int* __restrict__ counts,
                                                unsigned int* __restrict__ packed) {
  __shared__ int cur[NB];
  int g = blockIdx.x;
  for (int k = threadIdx.x; k < NB; k += 256) cur[k] = counts[k * GB + g];
  __syncthreads();
  int start = g * CHUNK;
  for (int gi = threadIdx.x; gi < CHUNK / 4; gi += 256) {
    int4 r4 = *reinterpret_cast<const int4*>(row + start + gi * 4);
    int4 c4 = *reinterpret_cast<const int4*>(col + start + gi * 4);
    int p0 = atomicAdd(&cur[r4.x >> 8], 1);
    int p1 = atomicAdd(&cur[r4.y >> 8], 1);
    int p2 = atomicAdd(&cur[r4.z >> 8], 1);
    int p3 = atomicAdd(&cur[r4.w >> 8], 1);
    packed[p0] = ((unsigned)(r4.x & 255) << 17) | (unsigned)c4.x;
    packed[p1] = ((unsigned)(r4.y & 255) << 17) | (unsigned)c4.y;
    packed[p2] = ((unsigned)(r4.z & 255) << 17) | (unsigned)c4.z;
    packed[p3] = ((unsigned)(r4.w & 255) << 17) | (unsigned)c4.w;
  }
}

// ---------------- pass C: per-bucket CSR finalize + fused x-cast ----------------

__global__ __launch_bounds__(256) void k_csr(const unsigned int* __restrict__ packed,
                                             const int* __restrict__ counts,
                                             int* __restrict__ rowptr,
                                             float* __restrict__ dis,
                                             int* __restrict__ csr_col,
                                             const float* __restrict__ x,
                                             unsigned short* __restrict__ xb,
                                             int N, int E) {
  __shared__ int rh[256];
  __shared__ int sc[256];
  __shared__ int cur[256];
  __shared__ float ldis[256];
  int b = blockIdx.x;
  int start = counts[b * GB];
  int end = (b + 1 < NB) ? counts[(b + 1) * GB] : E;

  rh[threadIdx.x] = 0;
  __syncthreads();
  for (int i = start + threadIdx.x; i < end; i += 256)
    atomicAdd(&rh[packed[i] >> 17], 1);
  __syncthreads();

  int v = rh[threadIdx.x];
  sc[threadIdx.x] = v;
  __syncthreads();
  for (int off = 1; off < 256; off <<= 1) {
    int t = (threadIdx.x >= off) ? sc[threadIdx.x - off] : 0;
    __syncthreads();
    sc[threadIdx.x] += t;
    __syncthreads();
  }
  int exc = sc[threadIdx.x] - v;

  float dv = 1.0f / sqrtf((float)v + 1e-12f);
  ldis[threadIdx.x] = dv;
  int gr = (b << 8) + threadIdx.x;
  if (gr < N) {
    rowptr[gr] = start + exc;
    dis[gr] = dv;
  }
  if (b == NB - 1 && threadIdx.x == 0) rowptr[N] = E;

  cur[threadIdx.x] = exc;
  __syncthreads();
  for (int i = start + threadIdx.x; i < end; i += 256) {
    unsigned p = packed[i];
    int lr = p >> 17;
    int c = (int)(p & 0x1FFFFu);
    int pos = atomicAdd(&cur[lr], 1);
    csr_col[start + pos] = c;
  }

  // fused cast: this bucket's rows of x -> bf16 * dis (coalesced float4 loop)
  int rows = min(256, N - (b << 8));
  if (rows > 0) {
    const float4* xs = reinterpret_cast<const float4*>(x + ((size_t)b << 8) * 32);
    ushort4* xd = reinterpret_cast<ushort4*>(xb + ((size_t)b << 8) * 32);
    for (int i = threadIdx.x; i < rows * 8; i += 256) {
      float ds = ldis[i >> 3];
      float4 vv = xs[i];
      xd[i] = make_ushort4(f2bf(vv.x * ds), f2bf(vv.y * ds),
                           f2bf(vv.z * ds), f2bf(vv.w * ds));
    }
  }
}

// ---------------- bf16 gather (2-deep unrolled): dst[r,:] = dis[r]*sum src[col,:] ----

template <int SQ>
static __device__ __forceinline__ void acc_bf(float* acc, const uint4* u) {
#pragma unroll
  for (int q = 0; q < SQ; ++q) {
    acc[8 * q + 0] += __uint_as_float(u[q].x << 16);
    acc[8 * q + 1] += __uint_as_float(u[q].x & 0xffff0000u);
    acc[8 * q + 2] += __uint_as_float(u[q].y << 16);
    acc[8 * q + 3] += __uint_as_float(u[q].y & 0xffff0000u);
    acc[8 * q + 4] += __uint_as_float(u[q].z << 16);
    acc[8 * q + 5] += __uint_as_float(u[q].z & 0xffff0000u);
    acc[8 * q + 6] += __uint_as_float(u[q].w << 16);
    acc[8 * q + 7] += __uint_as_float(u[q].w & 0xffff0000u);
  }
}

template <int LPR, int SQ>
__global__ __launch_bounds__(256) void k_gather_bf(const uint4* __restrict__ src,
                                                   const int* __restrict__ rowptr,
                                                   const int* __restrict__ csr_col,
                                                   const float* __restrict__ dis,
                                                   float* __restrict__ dst, int N) {
  constexpr int RQ = LPR * SQ;   // uint4s per row
  constexpr int W = RQ * 8;      // f32 values per row
  int t = blockIdx.x * 256 + threadIdx.x;
  int r = t / LPR, g = t % LPR;
  if (r >= N) return;
  int j = rowptr[r], end = rowptr[r + 1];

  float acc[SQ * 8];
#pragma unroll
  for (int q = 0; q < SQ * 8; ++q) acc[q] = 0.f;

  for (; j + 2 <= end; j += 2) {
    int c0 = csr_col[j], c1 = csr_col[j + 1];
    const uint4* sp0 = src + (size_t)c0 * RQ + g * SQ;
    const uint4* sp1 = src + (size_t)c1 * RQ + g * SQ;
    uint4 u0[SQ], u1[SQ];
#pragma unroll
    for (int q = 0; q < SQ; ++q) u0[q] = sp0[q];
#pragma unroll
    for (int q = 0; q < SQ; ++q) u1[q] = sp1[q];
    acc_bf<SQ>(acc, u0);
    acc_bf<SQ>(acc, u1);
  }
  if (j < end) {
    int c0 = csr_col[j];
    const uint4* sp0 = src + (size_t)c0 * RQ + g * SQ;
    uint4 u0[SQ];
#pragma unroll
    for (int q = 0; q < SQ; ++q) u0[q] = sp0[q];
    acc_bf<SQ>(acc, u0);
  }

  float ds = dis[r];
  float4* dp = reinterpret_cast<float4*>(dst + (size_t)r * W + g * (SQ * 8));
#pragma unroll
  for (int q = 0; q < SQ * 2; ++q)
    dp[q] = make_float4(ds * acc[4 * q + 0], ds * acc[4 * q + 1],
                        ds * acc[4 * q + 2], ds * acc[4 * q + 3]);
}

// ---------------- fused double GEMM: s2 = bf16(dis * (relu(g1@W1) @ W2)) ----------------
// launch_bounds(256,1): allow full VGPR budget (h[48]+o[48] live) — no scratch spills.

__global__ __launch_bounds__(256, 1) void k_gemm12(const float* __restrict__ g1,
                                                   const float* __restrict__ W1,
                                                   const float* __restrict__ W2,
                                                   const float* __restrict__ dis,
                                                   unsigned short* __restrict__ s2,
                                                   int N) {
  __shared__ float W1l[32 * 48];
  __shared__ float W2l[48 * 48];
  for (int i = threadIdx.x; i < 32 * 48; i += 256) W1l[i] = W1[i];
  for (int i = threadIdx.x; i < 48 * 48; i += 256) W2l[i] = W2[i];
  __syncthreads();
  int r = blockIdx.x * 256 + threadIdx.x;
  if (r >= N) return;

  float h[48];
#pragma unroll
  for (int f = 0; f < 48; ++f) h[f] = 0.f;
  const float4* xp = reinterpret_cast<const float4*>(g1 + (size_t)r * 32);
#pragma unroll
  for (int k4 = 0; k4 < 8; ++k4) {
    float4 v = xp[k4];
#pragma unroll
    for (int f = 0; f < 48; ++f) {
      h[f] = fmaf(v.x, W1l[(4 * k4 + 0) * 48 + f], h[f]);
      h[f] = fmaf(v.y, W1l[(4 * k4 + 1) * 48 + f], h[f]);
      h[f] = fmaf(v.z, W1l[(4 * k4 + 2) * 48 + f], h[f]);
      h[f] = fmaf(v.w, W1l[(4 * k4 + 3) * 48 + f], h[f]);
    }
  }
#pragma unroll
  for (int f = 0; f < 48; ++f) h[f] = fmaxf(h[f], 0.f);

  float o[48];
#pragma unroll
  for (int f = 0; f < 48; ++f) o[f] = 0.f;
#pragma unroll
  for (int k = 0; k < 48; ++k) {
    float hk = h[k];
#pragma unroll
    for (int f = 0; f < 48; ++f) o[f] = fmaf(hk, W2l[k * 48 + f], o[f]);
  }

  float ds = dis[r];
  uint4 pk[6];
  unsigned* pw = reinterpret_cast<unsigned*>(pk);
#pragma unroll
  for (int i = 0; i < 24; ++i)
    pw[i] = (unsigned)f2bf(o[2 * i] * ds) |
            ((unsigned)f2bf(o[2 * i + 1] * ds) << 16);
  uint4* op = reinterpret_cast<uint4*>(s2 + (size_t)r * 48);
#pragma unroll
  for (int q = 0; q < 6; ++q) op[q] = pk[q];
}

// ---------------- f32 GEMM with relu-in + dis epilogue (layer 3) ----------------

template <int K, int F, bool RELU>
__global__ __launch_bounds__(256) void k_gemm(const float* __restrict__ in,
                                              const float* __restrict__ W,
                                              const float* __restrict__ dis,
                                              float* __restrict__ out, int N) {
  __shared__ float Wl[K * F];
  for (int i = threadIdx.x; i < K * F; i += 256) Wl[i] = W[i];
  __syncthreads();
  int r = blockIdx.x * 256 + threadIdx.x;
  if (r >= N) return;

  float xr[K];
  const float4* xp = reinterpret_cast<const float4*>(in + (size_t)r * K);
#pragma unroll
  for (int k4 = 0; k4 < K / 4; ++k4) {
    float4 v = xp[k4];
    if (RELU) {
      v.x = fmaxf(v.x, 0.f); v.y = fmaxf(v.y, 0.f);
      v.z = fmaxf(v.z, 0.f); v.w = fmaxf(v.w, 0.f);
    }
    xr[4 * k4 + 0] = v.x; xr[4 * k4 + 1] = v.y;
    xr[4 * k4 + 2] = v.z; xr[4 * k4 + 3] = v.w;
  }

  float acc[F];
#pragma unroll
  for (int f = 0; f < F; ++f) acc[f] = 0.f;
#pragma unroll
  for (int k = 0; k < K; ++k) {
    float xk = xr[k];
#pragma unroll
    for (int f = 0; f < F; ++f) acc[f] = fmaf(xk, Wl[k * F + f], acc[f]);
  }

  float ds = dis[r];
  float4* op = reinterpret_cast<float4*>(out + (size_t)r * F);
#pragma unroll
  for (int f4 = 0; f4 < F / 4; ++f4)
    op[f4] = make_float4(ds * acc[4 * f4 + 0], ds * acc[4 * f4 + 1],
                         ds * acc[4 * f4 + 2], ds * acc[4 * f4 + 3]);
}

// ---------------- f32 gather (final 8-wide layer), 2-deep unrolled ----------------

template <int LPR, int FQ>
__global__ __launch_bounds__(256) void k_gather(const float* __restrict__ src,
                                                const int* __restrict__ rowptr,
                                                const int* __restrict__ csr_col,
                                                const float* __restrict__ dis,
                                                float* __restrict__ dst, int N) {
  constexpr int F = LPR * FQ * 4;
  int t = blockIdx.x * 256 + threadIdx.x;
  int r = t / LPR, g = t % LPR;
  if (r >= N) return;
  int j = rowptr[r], end = rowptr[r + 1];

  float acc[FQ * 4];
#pragma unroll
  for (int q = 0; q < FQ * 4; ++q) acc[q] = 0.f;

  for (; j + 2 <= end; j += 2) {
    int c0 = csr_col[j], c1 = csr_col[j + 1];
    const float4* sp0 =
        reinterpret_cast<const float4*>(src + (size_t)c0 * F + g * (FQ * 4));
    const float4* sp1 =
        reinterpret_cast<const float4*>(src + (size_t)c1 * F + g * (FQ * 4));
    float4 v0[FQ], v1[FQ];
#pragma unroll
    for (int q = 0; q < FQ; ++q) v0[q] = sp0[q];
#pragma unroll
    for (int q = 0; q < FQ; ++q) v1[q] = sp1[q];
#pragma unroll
    for (int q = 0; q < FQ; ++q) {
      acc[4 * q + 0] += v0[q].x + v1[q].x;
      acc[4 * q + 1] += v0[q].y + v1[q].y;
      acc[4 * q + 2] += v0[q].z + v1[q].z;
      acc[4 * q + 3] += v0[q].w + v1[q].w;
    }
  }
  if (j < end) {
    int c0 = csr_col[j];
    const float4* sp0 =
        reinterpret_cast<const float4*>(src + (size_t)c0 * F + g * (FQ * 4));
#pragma unroll
    for (int q = 0; q < FQ; ++q) {
      float4 v = sp0[q];
      acc[4 * q + 0] += v.x;
      acc[4 * q + 1] += v.y;
      acc[4 * q + 2] += v.z;
      acc[4 * q + 3] += v.w;
    }
  }

  float ds = dis[r];
  float4* dp = reinterpret_cast<float4*>(dst + (size_t)r * F + g * (FQ * 4));
#pragma unroll
  for (int q = 0; q < FQ; ++q)
    dp[q] = make_float4(ds * acc[4 * q + 0], ds * acc[4 * q + 1],
                        ds * acc[4 * q + 2], ds * acc[4 * q + 3]);
}

// ---------------- launch ----------------

extern "C" void kernel_launch(void* const* d_in, const int* in_sizes, int n_in,
                              void* d_out, int out_size, void* d_ws, size_t ws_size,
                              hipStream_t stream) {
  const float* x  = (const float*)d_in[0];
  const int*   ei = (const int*)d_in[1];
  const float* W1 = (const float*)d_in[2];
  const float* W2 = (const float*)d_in[3];
  const float* Wo = (const float*)d_in[4];
  float* out = (float*)d_out;

  const int N = NN, E = NE;
  const int* row = ei;
  const int* col = ei + E;
  const int scanG = (MCNT + 255) / 256;  // 382

  // workspace (words; every array 16B-aligned)
  int*   counts  = (int*)d_ws;                   // 97750 (pad 97752)
  int*   bsum    = counts + 97752;               // 382 (pad 384)
  int*   rowptr  = bsum + 384;                   // 100001 (pad 100008)
  float* dis     = (float*)(rowptr + 100008);    // 100000
  int*   csr_col = (int*)(dis + 100000);         // 1.6M
  float* A1      = (float*)(csr_col + NE);       // 4.8M floats
  float* A2      = A1 + 4800000;                 // 4.8M floats
  // aliases (lifetimes disjoint):
  unsigned int*   packed = (unsigned int*)A1;              // CSR build only
  unsigned short* s2     = (unsigned short*)A1;            // N*48 bf16
  float*          s3     = A1;                             // N*8 f32
  float*          g1     = A2;                             // N*32 f32
  unsigned short* xb     = (unsigned short*)(A2 + 3200000);// N*32 bf16
  float*          g2     = A2;                             // N*48 f32

  // ---- CSR build (+fused cast) ----
  k_hist<<<GB, 256, 0, stream>>>(row, counts);
  k_bsumG<<<scanG, 256, 0, stream>>>(counts, bsum, MCNT);
  k_scan_bsum<<<1, 256, 0, stream>>>(bsum, scanG);
  k_scan_finalG<<<scanG, 256, 0, stream>>>(counts, bsum, MCNT);
  k_bucket<<<GB, 256, 0, stream>>>(row, col, counts, packed);
  k_csr<<<NB, 256, 0, stream>>>(packed, counts, rowptr, dis, csr_col, x, xb, N, E);

  // ---- layer 1 (reassociated): g1 = dis⊙(Ā@(dis⊙x)) ----
  k_gather_bf<4, 1><<<(N * 4 + 255) / 256, 256, 0, stream>>>(
      (const uint4*)xb, rowptr, csr_col, dis, g1, N);

  // ---- fused GEMM1+GEMM2: s2 = bf16(dis * (relu(g1@W1)@W2)) ----
  k_gemm12<<<(N + 255) / 256, 256, 0, stream>>>(g1, W1, W2, dis, s2, N);

  // ---- layer 2 gather: g2 = dis⊙(Ā@s2) ----
  k_gather_bf<6, 1><<<(N * 6 + 255) / 256, 256, 0, stream>>>(
      (const uint4*)s2, rowptr, csr_col, dis, g2, N);

  // ---- layer 3: s3 = dis*(relu(g2)@Wo); out = dis⊙(Ā@s3) ----
  k_gemm<48, 8, true><<<(N + 255) / 256, 256, 0, stream>>>(g2, Wo, dis, s3, N);
  k_gather<2, 1><<<(N * 2 + 255) / 256, 256, 0, stream>>>(s3, rowptr, csr_col,
                                                          dis, out, N);
}

// Round 9
// 163.251 us; speedup vs baseline: 15.0329x; 1.0708x over previous
//
#include <hip/hip_runtime.h>
#include <hip/hip_bf16.h>
#include <cstdint>
#include <cstddef>

static constexpr int NN = 100000;   // nodes
static constexpr int NE = 1600000;  // edges
static constexpr int NB = 391;      // buckets of 256 rows
static constexpr int GB = 250;      // blocks in hist/bucket passes (250*6400 == NE)
static constexpr int CHUNK = NE / GB;             // 6400 (int4-aligned chunks)
static constexpr int MCNT = NB * GB;              // 97750

static __device__ __forceinline__ unsigned short f2bf(float f) {
  unsigned u = __float_as_uint(f);
  unsigned r = (u + 0x7fffu + ((u >> 16) & 1u)) >> 16;  // RNE
  return (unsigned short)r;
}

// ---------------- pass A: per-(bucket,block) histogram (int4 reads) ----------------

__global__ __launch_bounds__(256) void k_hist(const int* __restrict__ row,
                                              int* __restrict__ counts) {
  __shared__ int hist[NB];
  for (int k = threadIdx.x; k < NB; k += 256) hist[k] = 0;
  __syncthreads();
  int g = blockIdx.x;
  int start = g * CHUNK;
  for (int gi = threadIdx.x; gi < CHUNK / 4; gi += 256) {
    int4 r4 = *reinterpret_cast<const int4*>(row + start + gi * 4);
    atomicAdd(&hist[r4.x >> 8], 1);
    atomicAdd(&hist[r4.y >> 8], 1);
    atomicAdd(&hist[r4.z >> 8], 1);
    atomicAdd(&hist[r4.w >> 8], 1);
  }
  __syncthreads();
  for (int k = threadIdx.x; k < NB; k += 256) counts[k * GB + g] = hist[k];
}

// ---------------- generic 2-level exclusive scan ----------------

__global__ __launch_bounds__(256) void k_bsumG(const int* __restrict__ a,
                                               int* __restrict__ bsum, int M) {
  __shared__ int s[256];
  int i = blockIdx.x * 256 + threadIdx.x;
  s[threadIdx.x] = (i < M) ? a[i] : 0;
  __syncthreads();
  for (int off = 128; off > 0; off >>= 1) {
    if (threadIdx.x < off) s[threadIdx.x] += s[threadIdx.x + off];
    __syncthreads();
  }
  if (threadIdx.x == 0) bsum[blockIdx.x] = s[0];
}

__global__ __launch_bounds__(256) void k_scan_bsum(int* __restrict__ bsum, int nb) {
  __shared__ int s[256];
  __shared__ int carry;
  if (threadIdx.x == 0) carry = 0;
  __syncthreads();
  for (int base = 0; base < nb; base += 256) {
    int i = base + threadIdx.x;
    int v = (i < nb) ? bsum[i] : 0;
    s[threadIdx.x] = v;
    __syncthreads();
    for (int off = 1; off < 256; off <<= 1) {
      int t = (threadIdx.x >= off) ? s[threadIdx.x - off] : 0;
      __syncthreads();
      s[threadIdx.x] += t;
      __syncthreads();
    }
    int exc = carry + s[threadIdx.x] - v;
    if (i < nb) bsum[i] = exc;
    int tile_total = s[255];
    __syncthreads();
    if (threadIdx.x == 0) carry += tile_total;
    __syncthreads();
  }
}

__global__ __launch_bounds__(256) void k_scan_finalG(int* __restrict__ a,
                                                     const int* __restrict__ bsum,
                                                     int M) {
  __shared__ int s[256];
  int i = blockIdx.x * 256 + threadIdx.x;
  int v = (i < M) ? a[i] : 0;
  s[threadIdx.x] = v;
  __syncthreads();
  for (int off = 1; off < 256; off <<= 1) {
    int t = (threadIdx.x >= off) ? s[threadIdx.x - off] : 0;
    __syncthreads();
    s[threadIdx.x] += t;
    __syncthreads();
  }
  if (i < M) a[i] = bsum[blockIdx.x] + s[threadIdx.x] - v;
}

// ---------------- pass B: bucket-grouped packed edges (int4 reads) ----------------

__global__ __launch_bounds__(256) void k_bucket(const int* __restrict__ row,
                                                const int* __restrict__ col,
                                                const int* __restrict__ counts,
                                                unsigned int* __restrict__ packed) {
  __shared__ int cur[NB];
  int g = blockIdx.x;
  for (int k = threadIdx.x; k < NB; k += 256) cur[k] = counts[k * GB + g];
  __syncthreads();
  int start = g * CHUNK;
  for (int gi = threadIdx.x; gi < CHUNK / 4; gi += 256) {
    int4 r4 = *reinterpret_cast<const int4*>(row + start + gi * 4);
    int4 c4 = *reinterpret_cast<const int4*>(col + start + gi * 4);
    int p0 = atomicAdd(&cur[r4.x >> 8], 1);
    int p1 = atomicAdd(&cur[r4.y >> 8], 1);
    int p2 = atomicAdd(&cur[r4.z >> 8], 1);
    int p3 = atomicAdd(&cur[r4.w >> 8], 1);
    packed[p0] = ((unsigned)(r4.x & 255) << 17) | (unsigned)c4.x;
    packed[p1] = ((unsigned)(r4.y & 255) << 17) | (unsigned)c4.y;
    packed[p2] = ((unsigned)(r4.z & 255) << 17) | (unsigned)c4.z;
    packed[p3] = ((unsigned)(r4.w & 255) << 17) | (unsigned)c4.w;
  }
}

// ---------------- pass C: per-bucket CSR finalize + fused x-cast ----------------

__global__ __launch_bounds__(256) void k_csr(const unsigned int* __restrict__ packed,
                                             const int* __restrict__ counts,
                                             int* __restrict__ rowptr,
                                             float* __restrict__ dis,
                                             int* __restrict__ csr_col,
                                             const float* __restrict__ x,
                                             unsigned short* __restrict__ xb,
                                             int N, int E) {
  __shared__ int rh[256];
  __shared__ int sc[256];
  __shared__ int cur[256];
  __shared__ float ldis[256];
  int b = blockIdx.x;
  int start = counts[b * GB];
  int end = (b + 1 < NB) ? counts[(b + 1) * GB] : E;

  rh[threadIdx.x] = 0;
  __syncthreads();
  for (int i = start + threadIdx.x; i < end; i += 256)
    atomicAdd(&rh[packed[i] >> 17], 1);
  __syncthreads();

  int v = rh[threadIdx.x];
  sc[threadIdx.x] = v;
  __syncthreads();
  for (int off = 1; off < 256; off <<= 1) {
    int t = (threadIdx.x >= off) ? sc[threadIdx.x - off] : 0;
    __syncthreads();
    sc[threadIdx.x] += t;
    __syncthreads();
  }
  int exc = sc[threadIdx.x] - v;

  float dv = 1.0f / sqrtf((float)v + 1e-12f);
  ldis[threadIdx.x] = dv;
  int gr = (b << 8) + threadIdx.x;
  if (gr < N) {
    rowptr[gr] = start + exc;
    dis[gr] = dv;
  }
  if (b == NB - 1 && threadIdx.x == 0) rowptr[N] = E;

  cur[threadIdx.x] = exc;
  __syncthreads();
  for (int i = start + threadIdx.x; i < end; i += 256) {
    unsigned p = packed[i];
    int lr = p >> 17;
    int c = (int)(p & 0x1FFFFu);
    int pos = atomicAdd(&cur[lr], 1);
    csr_col[start + pos] = c;
  }

  // fused cast: this bucket's rows of x -> bf16 * dis (coalesced float4 loop)
  int rows = min(256, N - (b << 8));
  if (rows > 0) {
    const float4* xs = reinterpret_cast<const float4*>(x + ((size_t)b << 8) * 32);
    ushort4* xd = reinterpret_cast<ushort4*>(xb + ((size_t)b << 8) * 32);
    for (int i = threadIdx.x; i < rows * 8; i += 256) {
      float ds = ldis[i >> 3];
      float4 vv = xs[i];
      xd[i] = make_ushort4(f2bf(vv.x * ds), f2bf(vv.y * ds),
                           f2bf(vv.z * ds), f2bf(vv.w * ds));
    }
  }
}

// ---------------- bf16 accumulate helper ----------------

template <int SQ>
static __device__ __forceinline__ void acc_bf(float* acc, const uint4* u) {
#pragma unroll
  for (int q = 0; q < SQ; ++q) {
    acc[8 * q + 0] += __uint_as_float(u[q].x << 16);
    acc[8 * q + 1] += __uint_as_float(u[q].x & 0xffff0000u);
    acc[8 * q + 2] += __uint_as_float(u[q].y << 16);
    acc[8 * q + 3] += __uint_as_float(u[q].y & 0xffff0000u);
    acc[8 * q + 4] += __uint_as_float(u[q].z << 16);
    acc[8 * q + 5] += __uint_as_float(u[q].z & 0xffff0000u);
    acc[8 * q + 6] += __uint_as_float(u[q].w << 16);
    acc[8 * q + 7] += __uint_as_float(u[q].w & 0xffff0000u);
  }
}

// ---------------- bf16 gather (4-deep): dst[r,:] = dis[r]*sum src[col,:] ----------------

template <int LPR, int SQ>
__global__ __launch_bounds__(256) void k_gather_bf(const uint4* __restrict__ src,
                                                   const int* __restrict__ rowptr,
                                                   const int* __restrict__ csr_col,
                                                   const float* __restrict__ dis,
                                                   float* __restrict__ dst, int N) {
  constexpr int RQ = LPR * SQ;
  constexpr int W = RQ * 8;
  int t = blockIdx.x * 256 + threadIdx.x;
  int r = t / LPR, g = t % LPR;
  if (r >= N) return;
  int j = rowptr[r], end = rowptr[r + 1];

  float acc[SQ * 8];
#pragma unroll
  for (int q = 0; q < SQ * 8; ++q) acc[q] = 0.f;

  for (; j + 4 <= end; j += 4) {
    int c0 = csr_col[j], c1 = csr_col[j + 1], c2 = csr_col[j + 2], c3 = csr_col[j + 3];
    const uint4* sp0 = src + (size_t)c0 * RQ + g * SQ;
    const uint4* sp1 = src + (size_t)c1 * RQ + g * SQ;
    const uint4* sp2 = src + (size_t)c2 * RQ + g * SQ;
    const uint4* sp3 = src + (size_t)c3 * RQ + g * SQ;
    uint4 u0[SQ], u1[SQ], u2[SQ], u3[SQ];
#pragma unroll
    for (int q = 0; q < SQ; ++q) u0[q] = sp0[q];
#pragma unroll
    for (int q = 0; q < SQ; ++q) u1[q] = sp1[q];
#pragma unroll
    for (int q = 0; q < SQ; ++q) u2[q] = sp2[q];
#pragma unroll
    for (int q = 0; q < SQ; ++q) u3[q] = sp3[q];
    acc_bf<SQ>(acc, u0);
    acc_bf<SQ>(acc, u1);
    acc_bf<SQ>(acc, u2);
    acc_bf<SQ>(acc, u3);
  }
  for (; j < end; ++j) {
    int c0 = csr_col[j];
    const uint4* sp0 = src + (size_t)c0 * RQ + g * SQ;
    uint4 u0[SQ];
#pragma unroll
    for (int q = 0; q < SQ; ++q) u0[q] = sp0[q];
    acc_bf<SQ>(acc, u0);
  }

  float ds = dis[r];
  float4* dp = reinterpret_cast<float4*>(dst + (size_t)r * W + g * (SQ * 8));
#pragma unroll
  for (int q = 0; q < SQ * 2; ++q)
    dp[q] = make_float4(ds * acc[4 * q + 0], ds * acc[4 * q + 1],
                        ds * acc[4 * q + 2], ds * acc[4 * q + 3]);
}

// ---------------- fused double GEMM: s2 = bf16(dis*(relu(g1@W1)@W2)), padded 64 ----
// float4 LDS reads (ds_read_b128) — the b32-per-element form was LDS-issue-bound.

__global__ __launch_bounds__(256, 2) void k_gemm12(const float* __restrict__ g1,
                                                   const float* __restrict__ W1,
                                                   const float* __restrict__ W2,
                                                   const float* __restrict__ dis,
                                                   unsigned short* __restrict__ s2,
                                                   int N) {
  __shared__ float W1l[32 * 48];
  __shared__ float W2l[48 * 48];
  for (int i = threadIdx.x; i < 32 * 48; i += 256) W1l[i] = W1[i];
  for (int i = threadIdx.x; i < 48 * 48; i += 256) W2l[i] = W2[i];
  __syncthreads();
  int r = blockIdx.x * 256 + threadIdx.x;
  if (r >= N) return;

  float h[48];
#pragma unroll
  for (int f = 0; f < 48; ++f) h[f] = 0.f;
  const float4* xp = reinterpret_cast<const float4*>(g1 + (size_t)r * 32);
#pragma unroll
  for (int k4 = 0; k4 < 8; ++k4) {
    float4 v = xp[k4];
    const float* w0 = &W1l[(4 * k4 + 0) * 48];
    const float* w1 = &W1l[(4 * k4 + 1) * 48];
    const float* w2 = &W1l[(4 * k4 + 2) * 48];
    const float* w3 = &W1l[(4 * k4 + 3) * 48];
#pragma unroll
    for (int f4 = 0; f4 < 12; ++f4) {
      float4 a = *reinterpret_cast<const float4*>(w0 + 4 * f4);
      float4 b = *reinterpret_cast<const float4*>(w1 + 4 * f4);
      float4 c = *reinterpret_cast<const float4*>(w2 + 4 * f4);
      float4 d = *reinterpret_cast<const float4*>(w3 + 4 * f4);
      h[4 * f4 + 0] = fmaf(v.x, a.x, fmaf(v.y, b.x, fmaf(v.z, c.x, fmaf(v.w, d.x, h[4 * f4 + 0]))));
      h[4 * f4 + 1] = fmaf(v.x, a.y, fmaf(v.y, b.y, fmaf(v.z, c.y, fmaf(v.w, d.y, h[4 * f4 + 1]))));
      h[4 * f4 + 2] = fmaf(v.x, a.z, fmaf(v.y, b.z, fmaf(v.z, c.z, fmaf(v.w, d.z, h[4 * f4 + 2]))));
      h[4 * f4 + 3] = fmaf(v.x, a.w, fmaf(v.y, b.w, fmaf(v.z, c.w, fmaf(v.w, d.w, h[4 * f4 + 3]))));
    }
  }
#pragma unroll
  for (int f = 0; f < 48; ++f) h[f] = fmaxf(h[f], 0.f);

  float o[48];
#pragma unroll
  for (int f = 0; f < 48; ++f) o[f] = 0.f;
#pragma unroll
  for (int k = 0; k < 48; ++k) {
    float hk = h[k];
    const float* wr = &W2l[k * 48];
#pragma unroll
    for (int f4 = 0; f4 < 12; ++f4) {
      float4 w = *reinterpret_cast<const float4*>(wr + 4 * f4);
      o[4 * f4 + 0] = fmaf(hk, w.x, o[4 * f4 + 0]);
      o[4 * f4 + 1] = fmaf(hk, w.y, o[4 * f4 + 1]);
      o[4 * f4 + 2] = fmaf(hk, w.z, o[4 * f4 + 2]);
      o[4 * f4 + 3] = fmaf(hk, w.w, o[4 * f4 + 3]);
    }
  }

  float ds = dis[r];
  uint4 pk[8];
  unsigned* pw = reinterpret_cast<unsigned*>(pk);
#pragma unroll
  for (int i = 0; i < 24; ++i)
    pw[i] = (unsigned)f2bf(o[2 * i] * ds) |
            ((unsigned)f2bf(o[2 * i + 1] * ds) << 16);
#pragma unroll
  for (int i = 24; i < 32; ++i) pw[i] = 0u;  // pad features 48..63
  uint4* op = reinterpret_cast<uint4*>(s2 + (size_t)r * 64);
#pragma unroll
  for (int q = 0; q < 8; ++q) op[q] = pk[q];
}

// ---------------- fused layer-2 gather + layer-3 GEMM ----------------
// s3[r,:] = dis[r] * (relu(dis[r]*sum_j s2[col_j,:]) @ Wo)
// 8 lanes per row (padded 128B rows); shuffle-reduce over the 8-lane group.

__global__ __launch_bounds__(256) void k_gather_fc(const uint4* __restrict__ src,
                                                   const int* __restrict__ rowptr,
                                                   const int* __restrict__ csr_col,
                                                   const float* __restrict__ dis,
                                                   const float* __restrict__ Wo,
                                                   float* __restrict__ s3, int N) {
  __shared__ float Wol[64 * 8];
  for (int i = threadIdx.x; i < 512; i += 256) Wol[i] = (i < 384) ? Wo[i] : 0.f;
  __syncthreads();

  int t = blockIdx.x * 256 + threadIdx.x;
  int r = t >> 3, g = t & 7;
  if (r >= N) return;
  int j = rowptr[r], end = rowptr[r + 1];

  float acc[8];
#pragma unroll
  for (int q = 0; q < 8; ++q) acc[q] = 0.f;

  for (; j + 4 <= end; j += 4) {
    int c0 = csr_col[j], c1 = csr_col[j + 1], c2 = csr_col[j + 2], c3 = csr_col[j + 3];
    uint4 u0 = src[(size_t)c0 * 8 + g];
    uint4 u1 = src[(size_t)c1 * 8 + g];
    uint4 u2 = src[(size_t)c2 * 8 + g];
    uint4 u3 = src[(size_t)c3 * 8 + g];
    acc_bf<1>(acc, &u0);
    acc_bf<1>(acc, &u1);
    acc_bf<1>(acc, &u2);
    acc_bf<1>(acc, &u3);
  }
  for (; j < end; ++j) {
    uint4 u0 = src[(size_t)csr_col[j] * 8 + g];
    acc_bf<1>(acc, &u0);
  }

  float ds = dis[r];
  float v[8];
#pragma unroll
  for (int q = 0; q < 8; ++q) v[q] = fmaxf(ds * acc[q], 0.f);

  // partial = v(8 feats of this lane) @ Wo[8g..8g+8, 0..8)
  float p[8];
#pragma unroll
  for (int n = 0; n < 8; ++n) p[n] = 0.f;
  const int base = g * 8;
#pragma unroll
  for (int q = 0; q < 8; ++q) {
    float4 w0 = *reinterpret_cast<const float4*>(&Wol[(base + q) * 8]);
    float4 w1 = *reinterpret_cast<const float4*>(&Wol[(base + q) * 8 + 4]);
    p[0] = fmaf(v[q], w0.x, p[0]);
    p[1] = fmaf(v[q], w0.y, p[1]);
    p[2] = fmaf(v[q], w0.z, p[2]);
    p[3] = fmaf(v[q], w0.w, p[3]);
    p[4] = fmaf(v[q], w1.x, p[4]);
    p[5] = fmaf(v[q], w1.y, p[5]);
    p[6] = fmaf(v[q], w1.z, p[6]);
    p[7] = fmaf(v[q], w1.w, p[7]);
  }
  // reduce across the 8 lanes of this row
#pragma unroll
  for (int m = 1; m < 8; m <<= 1) {
#pragma unroll
    for (int n = 0; n < 8; ++n) p[n] += __shfl_xor(p[n], m, 64);
  }
  if (g < 2) {
    float4 w = make_float4(ds * p[4 * g + 0], ds * p[4 * g + 1],
                           ds * p[4 * g + 2], ds * p[4 * g + 3]);
    *reinterpret_cast<float4*>(s3 + (size_t)r * 8 + 4 * g) = w;
  }
}

// ---------------- f32 gather (final 8-wide layer), 2-deep ----------------

template <int LPR, int FQ>
__global__ __launch_bounds__(256) void k_gather(const float* __restrict__ src,
                                                const int* __restrict__ rowptr,
                                                const int* __restrict__ csr_col,
                                                const float* __restrict__ dis,
                                                float* __restrict__ dst, int N) {
  constexpr int F = LPR * FQ * 4;
  int t = blockIdx.x * 256 + threadIdx.x;
  int r = t / LPR, g = t % LPR;
  if (r >= N) return;
  int j = rowptr[r], end = rowptr[r + 1];

  float acc[FQ * 4];
#pragma unroll
  for (int q = 0; q < FQ * 4; ++q) acc[q] = 0.f;

  for (; j + 2 <= end; j += 2) {
    int c0 = csr_col[j], c1 = csr_col[j + 1];
    const float4* sp0 =
        reinterpret_cast<const float4*>(src + (size_t)c0 * F + g * (FQ * 4));
    const float4* sp1 =
        reinterpret_cast<const float4*>(src + (size_t)c1 * F + g * (FQ * 4));
    float4 v0[FQ], v1[FQ];
#pragma unroll
    for (int q = 0; q < FQ; ++q) v0[q] = sp0[q];
#pragma unroll
    for (int q = 0; q < FQ; ++q) v1[q] = sp1[q];
#pragma unroll
    for (int q = 0; q < FQ; ++q) {
      acc[4 * q + 0] += v0[q].x + v1[q].x;
      acc[4 * q + 1] += v0[q].y + v1[q].y;
      acc[4 * q + 2] += v0[q].z + v1[q].z;
      acc[4 * q + 3] += v0[q].w + v1[q].w;
    }
  }
  if (j < end) {
    int c0 = csr_col[j];
    const float4* sp0 =
        reinterpret_cast<const float4*>(src + (size_t)c0 * F + g * (FQ * 4));
#pragma unroll
    for (int q = 0; q < FQ; ++q) {
      float4 v = sp0[q];
      acc[4 * q + 0] += v.x;
      acc[4 * q + 1] += v.y;
      acc[4 * q + 2] += v.z;
      acc[4 * q + 3] += v.w;
    }
  }

  float ds = dis[r];
  float4* dp = reinterpret_cast<float4*>(dst + (size_t)r * F + g * (FQ * 4));
#pragma unroll
  for (int q = 0; q < FQ; ++q)
    dp[q] = make_float4(ds * acc[4 * q + 0], ds * acc[4 * q + 1],
                        ds * acc[4 * q + 2], ds * acc[4 * q + 3]);
}

// ---------------- launch ----------------

extern "C" void kernel_launch(void* const* d_in, const int* in_sizes, int n_in,
                              void* d_out, int out_size, void* d_ws, size_t ws_size,
                              hipStream_t stream) {
  const float* x  = (const float*)d_in[0];
  const int*   ei = (const int*)d_in[1];
  const float* W1 = (const float*)d_in[2];
  const float* W2 = (const float*)d_in[3];
  const float* Wo = (const float*)d_in[4];
  float* out = (float*)d_out;

  const int N = NN, E = NE;
  const int* row = ei;
  const int* col = ei + E;
  const int scanG = (MCNT + 255) / 256;  // 382

  // workspace layout (word offsets; all 16B aligned)
  int*   counts  = (int*)d_ws;                   // 97752
  int*   bsum    = counts + 97752;               // 384
  int*   rowptr  = bsum + 384;                   // 100008
  float* dis     = (float*)(rowptr + 100008);    // 100000
  int*   csr_col = (int*)(dis + 100000);         // 1.6M
  float* A1      = (float*)(csr_col + NE);       // 3.2M words
  float* A2      = A1 + 3200000;                 // 4.0M words
  float* s3      = A2 + 4000000;                 // 800K words (N*8 f32)
  // aliases (lifetimes disjoint):
  unsigned int*   packed = (unsigned int*)A1;               // CSR build only
  unsigned short* s2     = (unsigned short*)A1;             // N*64 bf16 (padded)
  float*          g1     = A2;                              // N*32 f32
  unsigned short* xb     = (unsigned short*)(A2 + 3200000); // N*32 bf16

  // ---- CSR build (+fused cast) ----
  k_hist<<<GB, 256, 0, stream>>>(row, counts);
  k_bsumG<<<scanG, 256, 0, stream>>>(counts, bsum, MCNT);
  k_scan_bsum<<<1, 256, 0, stream>>>(bsum, scanG);
  k_scan_finalG<<<scanG, 256, 0, stream>>>(counts, bsum, MCNT);
  k_bucket<<<GB, 256, 0, stream>>>(row, col, counts, packed);
  k_csr<<<NB, 256, 0, stream>>>(packed, counts, rowptr, dis, csr_col, x, xb, N, E);

  // ---- layer 1 (reassociated): g1 = dis⊙(Ā@(dis⊙x)) ----
  k_gather_bf<4, 1><<<(N * 4 + 255) / 256, 256, 0, stream>>>(
      (const uint4*)xb, rowptr, csr_col, dis, g1, N);

  // ---- fused GEMM1+GEMM2: s2 = bf16(dis * (relu(g1@W1)@W2)), padded to 64 ----
  k_gemm12<<<(N + 255) / 256, 256, 0, stream>>>(g1, W1, W2, dis, s2, N);

  // ---- fused layer-2 gather + layer-3 GEMM: s3 = dis*(relu(dis*(Ā@s2))@Wo) ----
  k_gather_fc<<<(N * 8 + 255) / 256, 256, 0, stream>>>(
      (const uint4*)s2, rowptr, csr_col, dis, Wo, s3, N);

  // ---- final gather: out = dis⊙(Ā@s3) ----
  k_gather<2, 1><<<(N * 2 + 255) / 256, 256, 0, stream>>>(s3, rowptr, csr_col,
                                                          dis, out, N);
}